// Round 1
// baseline (25011.679 us; speedup 1.0000x reference)
//
#include <hip/hip_runtime.h>
#include <hip/hip_bf16.h>
#include <math.h>

// ViT-Base forward: B=32, C=3, IMG=224, NP=14, PS=16, IN_DIM=768, D=768,
// NH=12, DH=64, L=12, MLP=3072, OUT=1000, S=197
#define VB   32
#define VD   768
#define VNH  12
#define VDH  64
#define VL   12
#define VMLP 3072
#define VOUT 1000
#define VS   197
#define VNPAT 196

// ---------------------------------------------------------------- patchify
// P[b*196+p][k], k = c*256 + iy*16 + ix, p = py*14 + px
__global__ __launch_bounds__(256) void patchify_kernel(
    const float* __restrict__ x, float* __restrict__ P) {
  int bp = blockIdx.x;                 // b*196 + p
  int b = bp / VNPAT, p = bp - b * VNPAT;
  int py = p / 14, px = p - py * 14;
  int t = threadIdx.x;
  int iy = t >> 4, ix = t & 15;
#pragma unroll
  for (int c = 0; c < 3; c++) {
    float val = x[(((size_t)(b * 3 + c) * 224) + (py * 16 + iy)) * 224 + px * 16 + ix];
    P[(size_t)bp * 768 + c * 256 + t] = val;
  }
}

// ---------------------------------------------------------------- cls + pos
__global__ __launch_bounds__(256) void addpos_kernel(
    const float* __restrict__ cls, const float* __restrict__ pos,
    float* __restrict__ out) {
  int bs = blockIdx.x;                 // b*197 + s
  int s = bs % VS;
  int t = threadIdx.x;
  size_t o = (size_t)bs * VD;
#pragma unroll
  for (int j = 0; j < 3; j++) {
    int d = j * 256 + t;
    if (s == 0) out[o + d] = cls[d] + pos[d];
    else        out[o + d] += pos[(size_t)s * VD + d];
  }
}

// ---------------------------------------------------------------- layernorm
__global__ __launch_bounds__(256) void ln_kernel(
    const float* __restrict__ x, float* __restrict__ y,
    const float* __restrict__ g, const float* __restrict__ b) {
  int row = blockIdx.x;
  int t = threadIdx.x;
  const float* xr = x + (size_t)row * VD;
  float v0 = xr[t], v1 = xr[t + 256], v2 = xr[t + 512];
  float s = v0 + v1 + v2;
  float ss = v0 * v0 + v1 * v1 + v2 * v2;
#pragma unroll
  for (int off = 32; off; off >>= 1) {
    s  += __shfl_down(s, off);
    ss += __shfl_down(ss, off);
  }
  __shared__ float red[10];
  int wid = t >> 6, lane = t & 63;
  if (lane == 0) { red[wid] = s; red[4 + wid] = ss; }
  __syncthreads();
  if (t == 0) {
    float S  = red[0] + red[1] + red[2] + red[3];
    float SS = red[4] + red[5] + red[6] + red[7];
    float mu = S * (1.0f / VD);
    float var = SS * (1.0f / VD) - mu * mu;
    red[8] = mu;
    red[9] = rsqrtf(var + 1e-5f);
  }
  __syncthreads();
  float mu = red[8], rs = red[9];
  float* yr = y + (size_t)row * VD;
  yr[t]       = (v0 - mu) * rs * g[t]       + b[t];
  yr[t + 256] = (v1 - mu) * rs * g[t + 256] + b[t + 256];
  yr[t + 512] = (v2 - mu) * rs * g[t + 512] + b[t + 512];
}

// ---------------------------------------------------------------- QKV proj
// q[b,h,s,e] = sum_d xn[b,s,h*64+d] * Wq[h,e,d] + bq[h,e]
__global__ __launch_bounds__(256) void qkv_kernel(
    const float* __restrict__ xn,
    const float* __restrict__ Wq, const float* __restrict__ Wk,
    const float* __restrict__ Wv,
    const float* __restrict__ bq, const float* __restrict__ bk,
    const float* __restrict__ bv,
    float* __restrict__ qo, float* __restrict__ ko, float* __restrict__ vo) {
  int bs = blockIdx.x;                 // b*197 + s
  int b = bs / VS, s = bs - b * VS;
  int t = threadIdx.x;
  __shared__ float xs[768];
  xs[t]       = xn[(size_t)bs * VD + t];
  xs[t + 256] = xn[(size_t)bs * VD + t + 256];
  xs[t + 512] = xn[(size_t)bs * VD + t + 512];
  __syncthreads();
#pragma unroll
  for (int oi = 0; oi < 9; oi++) {
    int o = oi * 256 + t;
    int which = o / 768;
    int rem = o - which * 768;
    int h = rem >> 6, e = rem & 63;
    const float* W; const float* bias; float* dst;
    if (which == 0)      { W = Wq; bias = bq; dst = qo; }
    else if (which == 1) { W = Wk; bias = bk; dst = ko; }
    else                 { W = Wv; bias = bv; dst = vo; }
    const float4* W4 = (const float4*)(W + ((size_t)h * 64 + e) * 64);
    const float* xh = xs + h * 64;
    float acc = bias[h * 64 + e];
#pragma unroll
    for (int d4 = 0; d4 < 16; d4++) {
      float4 w = W4[d4];
      acc += xh[d4 * 4 + 0] * w.x + xh[d4 * 4 + 1] * w.y +
             xh[d4 * 4 + 2] * w.z + xh[d4 * 4 + 3] * w.w;
    }
    dst[(((size_t)b * VNH + h) * VS + s) * VDH + e] = acc;
  }
}

// ---------------------------------------------------------------- attention
// one block per (b, h, sq): scores, softmax, AV, residual add into out
__global__ __launch_bounds__(256) void attn_kernel(
    const float* __restrict__ q, const float* __restrict__ k,
    const float* __restrict__ v, float* __restrict__ out) {
  int id = blockIdx.x;                 // (b*12+h)*197 + sq
  int bh = id / VS, sq = id - bh * VS;
  int b = bh / VNH, h = bh - b * VNH;
  int t = threadIdx.x;
  __shared__ float qs[64];
  __shared__ float p[VS];
  __shared__ float red[16];
  __shared__ float pacc[4][64];
  const float* kb = k + (size_t)bh * VS * VDH;
  const float* vb = v + (size_t)bh * VS * VDH;
  if (t < 64) qs[t] = q[((size_t)bh * VS + sq) * VDH + t];
  __syncthreads();
  float sc = -1e30f;
  if (t < VS) {
    const float4* kr = (const float4*)(kb + (size_t)t * VDH);
    float acc = 0.f;
#pragma unroll
    for (int d4 = 0; d4 < 16; d4++) {
      float4 kk = kr[d4];
      acc += qs[d4 * 4 + 0] * kk.x + qs[d4 * 4 + 1] * kk.y +
             qs[d4 * 4 + 2] * kk.z + qs[d4 * 4 + 3] * kk.w;
    }
    sc = acc * 0.125f;                 // 1/sqrt(64)
  }
  float m = sc;
#pragma unroll
  for (int off = 32; off; off >>= 1) m = fmaxf(m, __shfl_down(m, off));
  if ((t & 63) == 0) red[t >> 6] = m;
  __syncthreads();
  if (t == 0) red[8] = fmaxf(fmaxf(red[0], red[1]), fmaxf(red[2], red[3]));
  __syncthreads();
  float M = red[8];
  float e = (t < VS) ? __expf(sc - M) : 0.f;
  if (t < VS) p[t] = e;
  float ssum = e;
#pragma unroll
  for (int off = 32; off; off >>= 1) ssum += __shfl_down(ssum, off);
  if ((t & 63) == 0) red[4 + (t >> 6)] = ssum;
  __syncthreads();
  if (t == 0) red[9] = red[4] + red[5] + red[6] + red[7];
  __syncthreads();
  float inv = 1.0f / red[9];
  int e_dim = t & 63, chunk = t >> 6;
  float acc = 0.f;
  for (int kk = chunk; kk < VS; kk += 4)
    acc += p[kk] * vb[(size_t)kk * VDH + e_dim];
  pacc[chunk][e_dim] = acc;
  __syncthreads();
  if (t < 64) {
    float o = (pacc[0][t] + pacc[1][t] + pacc[2][t] + pacc[3][t]) * inv;
    out[((size_t)b * VS + sq) * VD + h * VDH + t] += o;
  }
}

// ---------------------------------------------------------------- GEMM
// C[M,N] = A[M,K] @ B[K,N] (+bias). EPI: 0=store 1=gelu-store 2=add-into-C
// REMAP: crow = row + row/196 + 1 (patch-token write into [B,197,D])
template <int EPI, int REMAP>
__global__ __launch_bounds__(256) void gemm_f32(
    const float* __restrict__ A, const float* __restrict__ Bm,
    const float* __restrict__ bias, float* __restrict__ C,
    int M, int N, int K) {
  __shared__ float As[16][68];
  __shared__ float Bs[16][68];
  int t = threadIdx.x;
  int bm = blockIdx.y * 64, bn = blockIdx.x * 64;
  int tm = (t & 15) * 4, tn = (t >> 4) * 4;
  float acc[4][4] = {};
  int arow = t >> 2;        // 0..63
  int ak   = (t & 3) * 4;   // 0,4,8,12
  int brow = t >> 4;        // 0..15
  int bcol = (t & 15) * 4;
  int grow = bm + arow;
  for (int k0 = 0; k0 < K; k0 += 16) {
    float4 av = make_float4(0.f, 0.f, 0.f, 0.f);
    if (grow < M) av = *(const float4*)(A + (size_t)grow * K + k0 + ak);
    float4 bv = *(const float4*)(Bm + (size_t)(k0 + brow) * N + bn + bcol);
    As[ak + 0][arow] = av.x; As[ak + 1][arow] = av.y;
    As[ak + 2][arow] = av.z; As[ak + 3][arow] = av.w;
    *(float4*)&Bs[brow][bcol] = bv;
    __syncthreads();
#pragma unroll
    for (int kk = 0; kk < 16; kk++) {
      float4 a = *(const float4*)&As[kk][tm];
      float4 b = *(const float4*)&Bs[kk][tn];
      acc[0][0] += a.x * b.x; acc[0][1] += a.x * b.y;
      acc[0][2] += a.x * b.z; acc[0][3] += a.x * b.w;
      acc[1][0] += a.y * b.x; acc[1][1] += a.y * b.y;
      acc[1][2] += a.y * b.z; acc[1][3] += a.y * b.w;
      acc[2][0] += a.z * b.x; acc[2][1] += a.z * b.y;
      acc[2][2] += a.z * b.z; acc[2][3] += a.z * b.w;
      acc[3][0] += a.w * b.x; acc[3][1] += a.w * b.y;
      acc[3][2] += a.w * b.z; acc[3][3] += a.w * b.w;
    }
    __syncthreads();
  }
#pragma unroll
  for (int i = 0; i < 4; i++) {
    int row = bm + tm + i;
    if (row >= M) continue;
    int crow = REMAP ? (row + row / 196 + 1) : row;
#pragma unroll
    for (int j = 0; j < 4; j++) {
      int col = bn + tn + j;
      float val = acc[i][j] + bias[col];
      float* cp = C + (size_t)crow * N + col;
      if (EPI == 1) {
        val = 0.5f * val * (1.0f + erff(val * 0.70710678118654752440f));
        *cp = val;
      } else if (EPI == 2) {
        *cp += val;
      } else {
        *cp = val;
      }
    }
  }
}

// ---------------------------------------------------------------- classifier
__global__ __launch_bounds__(256) void cls_kernel(
    const float* __restrict__ out_act, const float* __restrict__ Wc,
    const float* __restrict__ bc, float* __restrict__ y) {
  int b = blockIdx.x;
  int t = threadIdx.x;
  __shared__ float xs[768];
  __shared__ float logit[VOUT];
  __shared__ float red[10];
  const float* xr = out_act + (size_t)b * VS * VD;  // cls token row
  xs[t] = xr[t]; xs[t + 256] = xr[t + 256]; xs[t + 512] = xr[t + 512];
  __syncthreads();
  for (int j0 = 0; j0 < VOUT; j0 += 256) {
    int j = j0 + t;
    if (j < VOUT) {
      float acc = bc[j];
      for (int d = 0; d < VD; d++) acc += xs[d] * Wc[(size_t)d * VOUT + j];
      logit[j] = acc;
    }
  }
  __syncthreads();
  float m = -1e30f;
  for (int j = t; j < VOUT; j += 256) m = fmaxf(m, logit[j]);
#pragma unroll
  for (int off = 32; off; off >>= 1) m = fmaxf(m, __shfl_down(m, off));
  if ((t & 63) == 0) red[t >> 6] = m;
  __syncthreads();
  if (t == 0) red[8] = fmaxf(fmaxf(red[0], red[1]), fmaxf(red[2], red[3]));
  __syncthreads();
  float M = red[8];
  float s = 0.f;
  for (int j = t; j < VOUT; j += 256) {
    float e = expf(logit[j] - M);
    logit[j] = e;
    s += e;
  }
#pragma unroll
  for (int off = 32; off; off >>= 1) s += __shfl_down(s, off);
  if ((t & 63) == 0) red[4 + (t >> 6)] = s;
  __syncthreads();
  if (t == 0) red[9] = red[4] + red[5] + red[6] + red[7];
  __syncthreads();
  float inv = 1.0f / red[9];
  for (int j = t; j < VOUT; j += 256) y[(size_t)b * VOUT + j] = logit[j] * inv;
}

// ---------------------------------------------------------------- launch
extern "C" void kernel_launch(void* const* d_in, const int* in_sizes, int n_in,
                              void* d_out, int out_size, void* d_ws, size_t ws_size,
                              hipStream_t stream) {
  const float* x      = (const float*)d_in[0];
  const float* cls    = (const float*)d_in[1];
  const float* pos    = (const float*)d_in[2];
  const float* Wmap   = (const float*)d_in[3];
  const float* bmap   = (const float*)d_in[4];
  const float* ln1_g  = (const float*)d_in[5];
  const float* ln1_b  = (const float*)d_in[6];
  const float* Wq     = (const float*)d_in[7];
  const float* bq     = (const float*)d_in[8];
  const float* Wk     = (const float*)d_in[9];
  const float* bk     = (const float*)d_in[10];
  const float* Wv     = (const float*)d_in[11];
  const float* bv     = (const float*)d_in[12];
  const float* ln2_g  = (const float*)d_in[13];
  const float* ln2_b  = (const float*)d_in[14];
  const float* W1     = (const float*)d_in[15];
  const float* b1     = (const float*)d_in[16];
  const float* W2     = (const float*)d_in[17];
  const float* b2     = (const float*)d_in[18];
  const float* Wc     = (const float*)d_in[19];
  const float* bc     = (const float*)d_in[20];
  float* yout = (float*)d_out;

  const size_t nBS  = (size_t)VB * VS;          // 6304
  const size_t nBSD = nBS * VD;                 // 4,841,472
  float* out_act = (float*)d_ws;
  float* xn      = out_act + nBSD;
  float* qb      = xn + nBSD;
  float* kb      = qb + nBSD;
  float* vb      = kb + nBSD;
  float* hbuf    = vb + nBSD;                   // 6304*3072, patches alias here

  // 1. patchify into hbuf (as patch matrix)
  patchify_kernel<<<VB * VNPAT, 256, 0, stream>>>(x, hbuf);
  // 2. embed GEMM: tokens = P @ Wmap + bmap -> out_act rows [b*197 + 1 + p]
  {
    dim3 g(VD / 64, (VB * VNPAT) / 64);
    gemm_f32<0, 1><<<g, 256, 0, stream>>>(hbuf, Wmap, bmap, out_act,
                                          VB * VNPAT, VD, VD);
  }
  // 3. cls token + positional embedding
  addpos_kernel<<<(int)nBS, 256, 0, stream>>>(cls, pos, out_act);

  for (int l = 0; l < VL; l++) {
    // LN1
    ln_kernel<<<(int)nBS, 256, 0, stream>>>(out_act, xn,
                                            ln1_g + (size_t)l * VD,
                                            ln1_b + (size_t)l * VD);
    // QKV
    qkv_kernel<<<(int)nBS, 256, 0, stream>>>(
        xn,
        Wq + (size_t)l * VNH * VDH * VDH, Wk + (size_t)l * VNH * VDH * VDH,
        Wv + (size_t)l * VNH * VDH * VDH,
        bq + (size_t)l * VNH * VDH, bk + (size_t)l * VNH * VDH,
        bv + (size_t)l * VNH * VDH, qb, kb, vb);
    // attention + residual
    attn_kernel<<<VB * VNH * VS, 256, 0, stream>>>(qb, kb, vb, out_act);
    // LN2
    ln_kernel<<<(int)nBS, 256, 0, stream>>>(out_act, xn,
                                            ln2_g + (size_t)l * VD,
                                            ln2_b + (size_t)l * VD);
    // MLP1: h = gelu(xn @ W1 + b1)
    {
      dim3 g(VMLP / 64, ((int)nBS + 63) / 64);
      gemm_f32<1, 0><<<g, 256, 0, stream>>>(xn, W1 + (size_t)l * VD * VMLP,
                                            b1 + (size_t)l * VMLP, hbuf,
                                            (int)nBS, VMLP, VD);
    }
    // MLP2: out += h @ W2 + b2
    {
      dim3 g(VD / 64, ((int)nBS + 63) / 64);
      gemm_f32<2, 0><<<g, 256, 0, stream>>>(hbuf, W2 + (size_t)l * VMLP * VD,
                                            b2 + (size_t)l * VD, out_act,
                                            (int)nBS, VD, VMLP);
    }
  }
  // classifier + softmax
  cls_kernel<<<VB, 256, 0, stream>>>(out_act, Wc, bc, yout);
}

// Round 2
// 9578.876 us; speedup vs baseline: 2.6111x; 2.6111x over previous
//
#include <hip/hip_runtime.h>
#include <hip/hip_bf16.h>
#include <math.h>

// ViT-Base forward: B=32, C=3, IMG=224, NP=14, PS=16, IN_DIM=768, D=768,
// NH=12, DH=64, L=12, MLP=3072, OUT=1000, S=197
#define VB   32
#define VD   768
#define VNH  12
#define VDH  64
#define VL   12
#define VMLP 3072
#define VOUT 1000
#define VS   197
#define VNPAT 196

typedef _Float16 half8 __attribute__((ext_vector_type(8)));
typedef float f32x4 __attribute__((ext_vector_type(4)));

static __device__ __forceinline__ unsigned short f2h(float f) {
  _Float16 h = (_Float16)f;
  return __builtin_bit_cast(unsigned short, h);
}
static __device__ __forceinline__ float h2f(unsigned short u) {
  return (float)__builtin_bit_cast(_Float16, u);
}

// ---------------------------------------------------------------- patchify
// P[b*196+p][k] (fp16), k = c*256 + iy*16 + ix, p = py*14 + px
__global__ __launch_bounds__(256) void patchify_kernel(
    const float* __restrict__ x, unsigned short* __restrict__ P) {
  int bp = blockIdx.x;                 // b*196 + p
  int b = bp / VNPAT, p = bp - b * VNPAT;
  int py = p / 14, px = p - py * 14;
  int t = threadIdx.x;
  int iy = t >> 4, ix = t & 15;
#pragma unroll
  for (int c = 0; c < 3; c++) {
    float val = x[(((size_t)(b * 3 + c) * 224) + (py * 16 + iy)) * 224 + px * 16 + ix];
    P[(size_t)bp * 768 + c * 256 + t] = f2h(val);
  }
}

// ---------------------------------------------------------------- transpose
// W (fp32, K x N, layer-strided) -> WT (fp16, N x K)
__global__ __launch_bounds__(256) void transpose_kernel(
    const float* __restrict__ W, unsigned short* __restrict__ WT,
    int K, int N) {
  __shared__ float ts[64][65];
  int n0 = blockIdx.x * 64, k0 = blockIdx.y * 64;
  const float* Wl = W + (size_t)blockIdx.z * K * N;
  unsigned short* WTl = WT + (size_t)blockIdx.z * K * N;
  int t = threadIdx.x;
  int r = t >> 4, c4 = (t & 15) * 4;
#pragma unroll
  for (int p = 0; p < 4; ++p) {
    int row = p * 16 + r;
    float4 v = *(const float4*)(Wl + (size_t)(k0 + row) * N + n0 + c4);
    ts[row][c4 + 0] = v.x; ts[row][c4 + 1] = v.y;
    ts[row][c4 + 2] = v.z; ts[row][c4 + 3] = v.w;
  }
  __syncthreads();
#pragma unroll
  for (int p = 0; p < 4; ++p) {
    int n = p * 16 + r;
    ushort4 o;
    o.x = f2h(ts[c4 + 0][n]);
    o.y = f2h(ts[c4 + 1][n]);
    o.z = f2h(ts[c4 + 2][n]);
    o.w = f2h(ts[c4 + 3][n]);
    *(ushort4*)(WTl + (size_t)(n0 + n) * K + k0 + c4) = o;
  }
}

// ---------------------------------------------------------------- cls + pos
__global__ __launch_bounds__(256) void addpos_kernel(
    const float* __restrict__ cls, const float* __restrict__ pos,
    float* __restrict__ out) {
  int bs = blockIdx.x;                 // b*197 + s
  int s = bs % VS;
  int t = threadIdx.x;
  size_t o = (size_t)bs * VD;
#pragma unroll
  for (int j = 0; j < 3; j++) {
    int d = j * 256 + t;
    if (s == 0) out[o + d] = cls[d] + pos[d];
    else        out[o + d] += pos[(size_t)s * VD + d];
  }
}

// ---------------------------------------------------------------- layernorm
// fp32 in -> fp16 out
__global__ __launch_bounds__(256) void ln_kernel(
    const float* __restrict__ x, unsigned short* __restrict__ y,
    const float* __restrict__ g, const float* __restrict__ b) {
  int row = blockIdx.x;
  int t = threadIdx.x;
  const float* xr = x + (size_t)row * VD;
  float v0 = xr[t], v1 = xr[t + 256], v2 = xr[t + 512];
  float s = v0 + v1 + v2;
  float ss = v0 * v0 + v1 * v1 + v2 * v2;
#pragma unroll
  for (int off = 32; off; off >>= 1) {
    s  += __shfl_down(s, off);
    ss += __shfl_down(ss, off);
  }
  __shared__ float red[10];
  int wid = t >> 6, lane = t & 63;
  if (lane == 0) { red[wid] = s; red[4 + wid] = ss; }
  __syncthreads();
  if (t == 0) {
    float S  = red[0] + red[1] + red[2] + red[3];
    float SS = red[4] + red[5] + red[6] + red[7];
    float mu = S * (1.0f / VD);
    float var = SS * (1.0f / VD) - mu * mu;
    red[8] = mu;
    red[9] = rsqrtf(var + 1e-5f);
  }
  __syncthreads();
  float mu = red[8], rs = red[9];
  unsigned short* yr = y + (size_t)row * VD;
  yr[t]       = f2h((v0 - mu) * rs * g[t]       + b[t]);
  yr[t + 256] = f2h((v1 - mu) * rs * g[t + 256] + b[t + 256]);
  yr[t + 512] = f2h((v2 - mu) * rs * g[t + 512] + b[t + 512]);
}

// ---------------------------------------------------------------- QKV proj
// xn fp16; q[b,h,s,e] = sum_d xn[b,s,h*64+d] * Wq[h,e,d] + bq[h,e]  (fp32 out)
__global__ __launch_bounds__(256) void qkv_kernel(
    const unsigned short* __restrict__ xn,
    const float* __restrict__ Wq, const float* __restrict__ Wk,
    const float* __restrict__ Wv,
    const float* __restrict__ bq, const float* __restrict__ bk,
    const float* __restrict__ bv,
    float* __restrict__ qo, float* __restrict__ ko, float* __restrict__ vo) {
  int bs = blockIdx.x;                 // b*197 + s
  int b = bs / VS, s = bs - b * VS;
  int t = threadIdx.x;
  __shared__ float xs[768];
  xs[t]       = h2f(xn[(size_t)bs * VD + t]);
  xs[t + 256] = h2f(xn[(size_t)bs * VD + t + 256]);
  xs[t + 512] = h2f(xn[(size_t)bs * VD + t + 512]);
  __syncthreads();
#pragma unroll
  for (int oi = 0; oi < 9; oi++) {
    int o = oi * 256 + t;
    int which = o / 768;
    int rem = o - which * 768;
    int h = rem >> 6, e = rem & 63;
    const float* W; const float* bias; float* dst;
    if (which == 0)      { W = Wq; bias = bq; dst = qo; }
    else if (which == 1) { W = Wk; bias = bk; dst = ko; }
    else                 { W = Wv; bias = bv; dst = vo; }
    const float4* W4 = (const float4*)(W + ((size_t)h * 64 + e) * 64);
    const float* xh = xs + h * 64;
    float acc = bias[h * 64 + e];
#pragma unroll
    for (int d4 = 0; d4 < 16; d4++) {
      float4 w = W4[d4];
      acc += xh[d4 * 4 + 0] * w.x + xh[d4 * 4 + 1] * w.y +
             xh[d4 * 4 + 2] * w.z + xh[d4 * 4 + 3] * w.w;
    }
    dst[(((size_t)b * VNH + h) * VS + s) * VDH + e] = acc;
  }
}

// ---------------------------------------------------------------- attention
// one block per (b,h): K/V staged to LDS in 2 halves, thread-per-query,
// online softmax, residual add into out. All fp32.
__global__ __launch_bounds__(256) void attn_kernel(
    const float* __restrict__ q, const float* __restrict__ k,
    const float* __restrict__ v, float* __restrict__ out) {
  int bh = blockIdx.x;                 // b*12 + h
  int b = bh / VNH, h = bh - b * VNH;
  int t = threadIdx.x;
  __shared__ float Kl[99 * 64];
  __shared__ float Vl[99 * 64];
  const float* kb = k + (size_t)bh * VS * VDH;
  const float* vb = v + (size_t)bh * VS * VDH;
  float qr[64];
  float acc[64];
#pragma unroll
  for (int d = 0; d < 64; ++d) acc[d] = 0.f;
  float m = -3.0e38f, l = 0.f;
  if (t < VS) {
    const float4* q4 = (const float4*)(q + ((size_t)bh * VS + t) * VDH);
#pragma unroll
    for (int d4 = 0; d4 < 16; ++d4) {
      float4 qq = q4[d4];
      qr[d4 * 4 + 0] = qq.x * 0.125f;
      qr[d4 * 4 + 1] = qq.y * 0.125f;
      qr[d4 * 4 + 2] = qq.z * 0.125f;
      qr[d4 * 4 + 3] = qq.w * 0.125f;
    }
  }
  int s0 = 0;
  for (int st = 0; st < 2; ++st) {
    int cnt = (st == 0) ? 99 : 98;
    const float4* ks4 = (const float4*)(kb + (size_t)s0 * VDH);
    const float4* vs4 = (const float4*)(vb + (size_t)s0 * VDH);
    for (int idx = t; idx < cnt * 16; idx += 256) {
      ((float4*)Kl)[idx] = ks4[idx];
      ((float4*)Vl)[idx] = vs4[idx];
    }
    __syncthreads();
    if (t < VS) {
      for (int j = 0; j < cnt; ++j) {
        const float* kr = Kl + j * 64;
        float s = 0.f;
#pragma unroll
        for (int d = 0; d < 64; ++d) s += qr[d] * kr[d];
        if (s > m) {
          float al = __expf(m - s);
          l *= al;
#pragma unroll
          for (int d = 0; d < 64; ++d) acc[d] *= al;
          m = s;
        }
        float p = __expf(s - m);
        l += p;
        const float* vr = Vl + j * 64;
#pragma unroll
        for (int d = 0; d < 64; ++d) acc[d] += p * vr[d];
      }
    }
    __syncthreads();
    s0 += cnt;
  }
  if (t < VS) {
    float inv = 1.0f / l;
    float* op = out + ((size_t)b * VS + t) * VD + h * VDH;
#pragma unroll
    for (int d = 0; d < 64; ++d) op[d] += acc[d] * inv;
  }
}

// ---------------------------------------------------------------- MFMA GEMM
// C[M,N] = A[M,K](fp16) @ Bt[N,K](fp16)^T + bias
// EPI: 0 = store fp32 (REMAP optional), 1 = gelu -> store fp16, 2 = += fp32
#define BM 128
#define BN 128
#define BKK 64
#define LDA 72   // BKK + 8 pad (fp16 elems); 144B row stride, 16B-aligned

template <int EPI, int REMAP>
__global__ __launch_bounds__(256) void gemm_h(
    const unsigned short* __restrict__ A,
    const unsigned short* __restrict__ Bt,
    const float* __restrict__ bias, float* __restrict__ C,
    int M, int N, int K) {
  __shared__ unsigned short As[BM * LDA];
  __shared__ unsigned short Bs[BN * LDA];
  int t = threadIdx.x;
  int bm = blockIdx.y * BM, bn = blockIdx.x * BN;
  int lane = t & 63, wv = t >> 6;
  int wm = (wv & 1) * 64, wn = (wv >> 1) * 64;
  int l15 = lane & 15, l4 = lane >> 4;
  f32x4 acc[4][4] = {};
  int srow = t >> 3;          // 0..31
  int scol = (t & 7) * 8;     // 0..56 (fp16 elems, 16B chunks)
  for (int k0 = 0; k0 < K; k0 += BKK) {
#pragma unroll
    for (int p = 0; p < 4; ++p) {
      int row = p * 32 + srow;
      int grow = bm + row;
      uint4 val = make_uint4(0u, 0u, 0u, 0u);
      if (grow < M) val = *(const uint4*)(A + (size_t)grow * K + k0 + scol);
      *(uint4*)(&As[row * LDA + scol]) = val;
    }
#pragma unroll
    for (int p = 0; p < 4; ++p) {
      int row = p * 32 + srow;
      uint4 val = *(const uint4*)(Bt + (size_t)(bn + row) * K + k0 + scol);
      *(uint4*)(&Bs[row * LDA + scol]) = val;
    }
    __syncthreads();
#pragma unroll
    for (int kk = 0; kk < BKK; kk += 32) {
      half8 af[4], bf[4];
#pragma unroll
      for (int i = 0; i < 4; ++i)
        af[i] = *(const half8*)(&As[(wm + i * 16 + l15) * LDA + kk + l4 * 8]);
#pragma unroll
      for (int j = 0; j < 4; ++j)
        bf[j] = *(const half8*)(&Bs[(wn + j * 16 + l15) * LDA + kk + l4 * 8]);
#pragma unroll
      for (int i = 0; i < 4; ++i)
#pragma unroll
        for (int j = 0; j < 4; ++j)
          acc[i][j] = __builtin_amdgcn_mfma_f32_16x16x32_f16(
              af[i], bf[j], acc[i][j], 0, 0, 0);
    }
    __syncthreads();
  }
#pragma unroll
  for (int i = 0; i < 4; ++i) {
#pragma unroll
    for (int j = 0; j < 4; ++j) {
#pragma unroll
      for (int r = 0; r < 4; ++r) {
        int row = bm + wm + i * 16 + l4 * 4 + r;
        int col = bn + wn + j * 16 + l15;
        if (row < M) {
          float val = acc[i][j][r] + bias[col];
          if (EPI == 0) {
            int crow = REMAP ? (row + row / 196 + 1) : row;
            C[(size_t)crow * N + col] = val;
          } else if (EPI == 1) {
            val = 0.5f * val * (1.0f + erff(val * 0.70710678118654752440f));
            ((unsigned short*)C)[(size_t)row * N + col] = f2h(val);
          } else {
            C[(size_t)row * N + col] += val;
          }
        }
      }
    }
  }
}

// ---------------------------------------------------------------- classifier
__global__ __launch_bounds__(256) void cls_kernel(
    const float* __restrict__ out_act, const float* __restrict__ Wc,
    const float* __restrict__ bc, float* __restrict__ y) {
  int b = blockIdx.x;
  int t = threadIdx.x;
  __shared__ float xs[768];
  __shared__ float logit[VOUT];
  __shared__ float red[10];
  const float* xr = out_act + (size_t)b * VS * VD;  // cls token row
  xs[t] = xr[t]; xs[t + 256] = xr[t + 256]; xs[t + 512] = xr[t + 512];
  __syncthreads();
  for (int j0 = 0; j0 < VOUT; j0 += 256) {
    int j = j0 + t;
    if (j < VOUT) {
      float acc = bc[j];
      for (int d = 0; d < VD; d++) acc += xs[d] * Wc[(size_t)d * VOUT + j];
      logit[j] = acc;
    }
  }
  __syncthreads();
  float m = -1e30f;
  for (int j = t; j < VOUT; j += 256) m = fmaxf(m, logit[j]);
#pragma unroll
  for (int off = 32; off; off >>= 1) m = fmaxf(m, __shfl_down(m, off));
  if ((t & 63) == 0) red[t >> 6] = m;
  __syncthreads();
  if (t == 0) red[8] = fmaxf(fmaxf(red[0], red[1]), fmaxf(red[2], red[3]));
  __syncthreads();
  float M = red[8];
  float s = 0.f;
  for (int j = t; j < VOUT; j += 256) {
    float e = expf(logit[j] - M);
    logit[j] = e;
    s += e;
  }
#pragma unroll
  for (int off = 32; off; off >>= 1) s += __shfl_down(s, off);
  if ((t & 63) == 0) red[4 + (t >> 6)] = s;
  __syncthreads();
  if (t == 0) red[9] = red[4] + red[5] + red[6] + red[7];
  __syncthreads();
  float inv = 1.0f / red[9];
  for (int j = t; j < VOUT; j += 256) y[(size_t)b * VOUT + j] = logit[j] * inv;
}

// ---------------------------------------------------------------- launch
extern "C" void kernel_launch(void* const* d_in, const int* in_sizes, int n_in,
                              void* d_out, int out_size, void* d_ws, size_t ws_size,
                              hipStream_t stream) {
  const float* x      = (const float*)d_in[0];
  const float* cls    = (const float*)d_in[1];
  const float* pos    = (const float*)d_in[2];
  const float* Wmap   = (const float*)d_in[3];
  const float* bmap   = (const float*)d_in[4];
  const float* ln1_g  = (const float*)d_in[5];
  const float* ln1_b  = (const float*)d_in[6];
  const float* Wq     = (const float*)d_in[7];
  const float* bq     = (const float*)d_in[8];
  const float* Wk     = (const float*)d_in[9];
  const float* bk     = (const float*)d_in[10];
  const float* Wv     = (const float*)d_in[11];
  const float* bv     = (const float*)d_in[12];
  const float* ln2_g  = (const float*)d_in[13];
  const float* ln2_b  = (const float*)d_in[14];
  const float* W1     = (const float*)d_in[15];
  const float* b1     = (const float*)d_in[16];
  const float* W2     = (const float*)d_in[17];
  const float* b2     = (const float*)d_in[18];
  const float* Wc     = (const float*)d_in[19];
  const float* bc     = (const float*)d_in[20];
  float* yout = (float*)d_out;

  const size_t nBS  = (size_t)VB * VS;          // 6304
  const size_t nBSD = nBS * VD;                 // 4,841,472
  char* base = (char*)d_ws;
  size_t off = 0;
  float* out_act = (float*)(base + off);      off += nBSD * 4;
  unsigned short* xnb = (unsigned short*)(base + off); off += nBSD * 2;
  float* qb = (float*)(base + off);           off += nBSD * 4;
  float* kb = (float*)(base + off);           off += nBSD * 4;
  float* vb = (float*)(base + off);           off += nBSD * 4;
  unsigned short* hbuf = (unsigned short*)(base + off); off += nBS * VMLP * 2;
  unsigned short* wmapT = (unsigned short*)(base + off); off += (size_t)VD * VD * 2;
  unsigned short* w1T = (unsigned short*)(base + off);   off += (size_t)VL * VMLP * VD * 2;
  unsigned short* w2T = (unsigned short*)(base + off);   off += (size_t)VL * VD * VMLP * 2;

  // weight transposes (fp32 -> fp16, K x N -> N x K)
  transpose_kernel<<<dim3(12, 12, 1), 256, 0, stream>>>(Wmap, wmapT, VD, VD);
  transpose_kernel<<<dim3(48, 12, VL), 256, 0, stream>>>(W1, w1T, VD, VMLP);
  transpose_kernel<<<dim3(12, 48, VL), 256, 0, stream>>>(W2, w2T, VMLP, VD);

  // patchify (fp16 patches into hbuf)
  patchify_kernel<<<VB * VNPAT, 256, 0, stream>>>(x, hbuf);
  // embed GEMM: out rows [b*197 + 1 + p]
  gemm_h<0, 1><<<dim3(VD / BN, (VB * VNPAT) / BM), 256, 0, stream>>>(
      hbuf, wmapT, bmap, out_act, VB * VNPAT, VD, VD);
  // cls token + positional embedding
  addpos_kernel<<<(int)nBS, 256, 0, stream>>>(cls, pos, out_act);

  for (int l = 0; l < VL; l++) {
    ln_kernel<<<(int)nBS, 256, 0, stream>>>(out_act, xnb,
                                            ln1_g + (size_t)l * VD,
                                            ln1_b + (size_t)l * VD);
    qkv_kernel<<<(int)nBS, 256, 0, stream>>>(
        xnb,
        Wq + (size_t)l * VNH * VDH * VDH, Wk + (size_t)l * VNH * VDH * VDH,
        Wv + (size_t)l * VNH * VDH * VDH,
        bq + (size_t)l * VNH * VDH, bk + (size_t)l * VNH * VDH,
        bv + (size_t)l * VNH * VDH, qb, kb, vb);
    attn_kernel<<<VB * VNH, 256, 0, stream>>>(qb, kb, vb, out_act);
    ln_kernel<<<(int)nBS, 256, 0, stream>>>(out_act, xnb,
                                            ln2_g + (size_t)l * VD,
                                            ln2_b + (size_t)l * VD);
    // MLP1: h = gelu(xn @ W1 + b1) -> fp16 hbuf
    gemm_h<1, 0><<<dim3(VMLP / BN, ((int)nBS + BM - 1) / BM), 256, 0, stream>>>(
        xnb, w1T + (size_t)l * VMLP * VD, b1 + (size_t)l * VMLP,
        (float*)hbuf, (int)nBS, VMLP, VD);
    // MLP2: out += h @ W2 + b2
    gemm_h<2, 0><<<dim3(VD / BN, ((int)nBS + BM - 1) / BM), 256, 0, stream>>>(
        hbuf, w2T + (size_t)l * VD * VMLP, b2 + (size_t)l * VD,
        out_act, (int)nBS, VD, VMLP);
  }
  cls_kernel<<<VB, 256, 0, stream>>>(out_act, Wc, bc, yout);
}

// Round 3
// 5266.692 us; speedup vs baseline: 4.7490x; 1.8188x over previous
//
#include <hip/hip_runtime.h>
#include <hip/hip_bf16.h>
#include <math.h>

// ViT-Base forward: B=32, C=3, IMG=224, NP=14, PS=16, IN_DIM=768, D=768,
// NH=12, DH=64, L=12, MLP=3072, OUT=1000, S=197
#define VB   32
#define VD   768
#define VNH  12
#define VDH  64
#define VL   12
#define VMLP 3072
#define VOUT 1000
#define VS   197
#define VNPAT 196

typedef _Float16 half8 __attribute__((ext_vector_type(8)));
typedef float f32x4 __attribute__((ext_vector_type(4)));

static __device__ __forceinline__ unsigned short f2h(float f) {
  _Float16 h = (_Float16)f;
  return __builtin_bit_cast(unsigned short, h);
}
static __device__ __forceinline__ float h2f(unsigned short u) {
  return (float)__builtin_bit_cast(_Float16, u);
}

// ---------------------------------------------------------------- patchify
// P[b*196+p][k] (fp16), k = c*256 + iy*16 + ix, p = py*14 + px
__global__ __launch_bounds__(256) void patchify_kernel(
    const float* __restrict__ x, unsigned short* __restrict__ P) {
  int bp = blockIdx.x;                 // b*196 + p
  int b = bp / VNPAT, p = bp - b * VNPAT;
  int py = p / 14, px = p - py * 14;
  int t = threadIdx.x;
  int iy = t >> 4, ix = t & 15;
#pragma unroll
  for (int c = 0; c < 3; c++) {
    float val = x[(((size_t)(b * 3 + c) * 224) + (py * 16 + iy)) * 224 + px * 16 + ix];
    P[(size_t)bp * 768 + c * 256 + t] = f2h(val);
  }
}

// ---------------------------------------------------------------- transpose
// W (fp32, K x N, layer-strided) -> WT (fp16, N x K)
__global__ __launch_bounds__(256) void transpose_kernel(
    const float* __restrict__ W, unsigned short* __restrict__ WT,
    int K, int N) {
  __shared__ float ts[64][65];
  int n0 = blockIdx.x * 64, k0 = blockIdx.y * 64;
  const float* Wl = W + (size_t)blockIdx.z * K * N;
  unsigned short* WTl = WT + (size_t)blockIdx.z * K * N;
  int t = threadIdx.x;
  int r = t >> 4, c4 = (t & 15) * 4;
#pragma unroll
  for (int p = 0; p < 4; ++p) {
    int row = p * 16 + r;
    float4 v = *(const float4*)(Wl + (size_t)(k0 + row) * N + n0 + c4);
    ts[row][c4 + 0] = v.x; ts[row][c4 + 1] = v.y;
    ts[row][c4 + 2] = v.z; ts[row][c4 + 3] = v.w;
  }
  __syncthreads();
#pragma unroll
  for (int p = 0; p < 4; ++p) {
    int n = p * 16 + r;
    ushort4 o;
    o.x = f2h(ts[c4 + 0][n]);
    o.y = f2h(ts[c4 + 1][n]);
    o.z = f2h(ts[c4 + 2][n]);
    o.w = f2h(ts[c4 + 3][n]);
    *(ushort4*)(WTl + (size_t)(n0 + n) * K + k0 + c4) = o;
  }
}

// ---------------------------------------------------------------- pack QKV
// Wp[l][h][n][d] fp16, n in 0..191: 0-63 = Wq[e][d], 64-127 = Wk, 128-191 = Wv
__global__ __launch_bounds__(256) void pack_qkv_kernel(
    const float* __restrict__ Wq, const float* __restrict__ Wk,
    const float* __restrict__ Wv, unsigned short* __restrict__ Wp) {
  size_t idx = (size_t)blockIdx.x * 256 + threadIdx.x;  // < 12*12*192*64
  int d = idx & 63;
  size_t r = idx >> 6;            // lh*192 + n
  int n = (int)(r % 192);
  size_t lh = r / 192;            // l*12 + h
  int which = n >> 6, e = n & 63;
  const float* W = which == 0 ? Wq : which == 1 ? Wk : Wv;
  Wp[idx] = f2h(W[(lh * 64 + e) * 64 + d]);
}

// ---------------------------------------------------------------- cls + pos
__global__ __launch_bounds__(256) void addpos_kernel(
    const float* __restrict__ cls, const float* __restrict__ pos,
    float* __restrict__ out) {
  int bs = blockIdx.x;                 // b*197 + s
  int s = bs % VS;
  int t = threadIdx.x;
  size_t o = (size_t)bs * VD;
#pragma unroll
  for (int j = 0; j < 3; j++) {
    int d = j * 256 + t;
    if (s == 0) out[o + d] = cls[d] + pos[d];
    else        out[o + d] += pos[(size_t)s * VD + d];
  }
}

// ---------------------------------------------------------------- layernorm
// fp32 in -> fp16 out
__global__ __launch_bounds__(256) void ln_kernel(
    const float* __restrict__ x, unsigned short* __restrict__ y,
    const float* __restrict__ g, const float* __restrict__ b) {
  int row = blockIdx.x;
  int t = threadIdx.x;
  const float* xr = x + (size_t)row * VD;
  float v0 = xr[t], v1 = xr[t + 256], v2 = xr[t + 512];
  float s = v0 + v1 + v2;
  float ss = v0 * v0 + v1 * v1 + v2 * v2;
#pragma unroll
  for (int off = 32; off; off >>= 1) {
    s  += __shfl_down(s, off);
    ss += __shfl_down(ss, off);
  }
  __shared__ float red[10];
  int wid = t >> 6, lane = t & 63;
  if (lane == 0) { red[wid] = s; red[4 + wid] = ss; }
  __syncthreads();
  if (t == 0) {
    float S  = red[0] + red[1] + red[2] + red[3];
    float SS = red[4] + red[5] + red[6] + red[7];
    float mu = S * (1.0f / VD);
    float var = SS * (1.0f / VD) - mu * mu;
    red[8] = mu;
    red[9] = rsqrtf(var + 1e-5f);
  }
  __syncthreads();
  float mu = red[8], rs = red[9];
  unsigned short* yr = y + (size_t)row * VD;
  yr[t]       = f2h((v0 - mu) * rs * g[t]       + b[t]);
  yr[t + 256] = f2h((v1 - mu) * rs * g[t + 256] + b[t + 256]);
  yr[t + 512] = f2h((v2 - mu) * rs * g[t + 512] + b[t + 512]);
}

// ---------------------------------------------------------------- QKV GEMM
// per head h: C[6304, 192] = xn[:, h*64:(h+1)*64] @ Wp[h]^T (+bias)
// out: q/k/v[b,h,s,e] fp32
__global__ __launch_bounds__(256) void qkv_gemm(
    const unsigned short* __restrict__ xn,     // [6304, 768] fp16
    const unsigned short* __restrict__ Wp,     // [12][192][64] fp16 (layer base)
    const float* __restrict__ bq, const float* __restrict__ bk,
    const float* __restrict__ bv,              // [12][64] each (layer base)
    float* __restrict__ qo, float* __restrict__ ko, float* __restrict__ vo) {
  __shared__ unsigned short As[128 * 72];
  __shared__ unsigned short Bs[192 * 72];
  int h = blockIdx.y;
  int bm = blockIdx.x * 128;
  int t = threadIdx.x;
  int srow = t >> 3;          // 0..31
  int scol = (t & 7) * 8;     // 0..56
#pragma unroll
  for (int p = 0; p < 4; ++p) {
    int row = p * 32 + srow;
    int grow = bm + row;
    uint4 val = make_uint4(0u, 0u, 0u, 0u);
    if (grow < VB * VS)
      val = *(const uint4*)(xn + (size_t)grow * VD + h * 64 + scol);
    *(uint4*)(&As[row * 72 + scol]) = val;
  }
#pragma unroll
  for (int p = 0; p < 6; ++p) {
    int row = p * 32 + srow;
    uint4 val = *(const uint4*)(Wp + ((size_t)h * 192 + row) * 64 + scol);
    *(uint4*)(&Bs[row * 72 + scol]) = val;
  }
  __syncthreads();
  int lane = t & 63, wv = t >> 6;
  int wm = (wv & 1) * 64, wn = (wv >> 1) * 96;
  int l15 = lane & 15, l4 = lane >> 4;
  f32x4 acc[4][6] = {};
#pragma unroll
  for (int kk = 0; kk < 64; kk += 32) {
    half8 af[4], bf[6];
#pragma unroll
    for (int i = 0; i < 4; ++i)
      af[i] = *(const half8*)(&As[(wm + i * 16 + l15) * 72 + kk + l4 * 8]);
#pragma unroll
    for (int j = 0; j < 6; ++j)
      bf[j] = *(const half8*)(&Bs[(wn + j * 16 + l15) * 72 + kk + l4 * 8]);
#pragma unroll
    for (int i = 0; i < 4; ++i)
#pragma unroll
      for (int j = 0; j < 6; ++j)
        acc[i][j] = __builtin_amdgcn_mfma_f32_16x16x32_f16(
            af[i], bf[j], acc[i][j], 0, 0, 0);
  }
#pragma unroll
  for (int j = 0; j < 6; ++j) {
    int n = wn + j * 16 + l15;           // 0..191
    int which = n >> 6, e = n & 63;
    float* dst = which == 0 ? qo : which == 1 ? ko : vo;
    const float* bias = which == 0 ? bq : which == 1 ? bk : bv;
    float bval = bias[h * 64 + e];
#pragma unroll
    for (int i = 0; i < 4; ++i) {
#pragma unroll
      for (int r = 0; r < 4; ++r) {
        int row = bm + wm + i * 16 + l4 * 4 + r;   // token index
        if (row < VB * VS) {
          int b = row / VS, s = row - b * VS;
          dst[(((size_t)b * VNH + h) * VS + s) * VDH + e] = acc[i][j][r] + bval;
        }
      }
    }
  }
}

// ---------------------------------------------------------------- attention
// one block per (b,h): K/V staged to LDS in 2 halves, thread-per-query,
// online softmax, residual add into out. All fp32.
__global__ __launch_bounds__(256) void attn_kernel(
    const float* __restrict__ q, const float* __restrict__ k,
    const float* __restrict__ v, float* __restrict__ out) {
  int bh = blockIdx.x;                 // b*12 + h
  int b = bh / VNH, h = bh - b * VNH;
  int t = threadIdx.x;
  __shared__ float Kl[99 * 64];
  __shared__ float Vl[99 * 64];
  const float* kb = k + (size_t)bh * VS * VDH;
  const float* vb = v + (size_t)bh * VS * VDH;
  float qr[64];
  float acc[64];
#pragma unroll
  for (int d = 0; d < 64; ++d) acc[d] = 0.f;
  float m = -3.0e38f, l = 0.f;
  if (t < VS) {
    const float4* q4 = (const float4*)(q + ((size_t)bh * VS + t) * VDH);
#pragma unroll
    for (int d4 = 0; d4 < 16; ++d4) {
      float4 qq = q4[d4];
      qr[d4 * 4 + 0] = qq.x * 0.125f;
      qr[d4 * 4 + 1] = qq.y * 0.125f;
      qr[d4 * 4 + 2] = qq.z * 0.125f;
      qr[d4 * 4 + 3] = qq.w * 0.125f;
    }
  }
  int s0 = 0;
  for (int st = 0; st < 2; ++st) {
    int cnt = (st == 0) ? 99 : 98;
    const float4* ks4 = (const float4*)(kb + (size_t)s0 * VDH);
    const float4* vs4 = (const float4*)(vb + (size_t)s0 * VDH);
    for (int idx = t; idx < cnt * 16; idx += 256) {
      ((float4*)Kl)[idx] = ks4[idx];
      ((float4*)Vl)[idx] = vs4[idx];
    }
    __syncthreads();
    if (t < VS) {
      for (int j = 0; j < cnt; ++j) {
        const float* kr = Kl + j * 64;
        float s = 0.f;
#pragma unroll
        for (int d = 0; d < 64; ++d) s += qr[d] * kr[d];
        if (s > m) {
          float al = __expf(m - s);
          l *= al;
#pragma unroll
          for (int d = 0; d < 64; ++d) acc[d] *= al;
          m = s;
        }
        float p = __expf(s - m);
        l += p;
        const float* vr = Vl + j * 64;
#pragma unroll
        for (int d = 0; d < 64; ++d) acc[d] += p * vr[d];
      }
    }
    __syncthreads();
    s0 += cnt;
  }
  if (t < VS) {
    float inv = 1.0f / l;
    float* op = out + ((size_t)b * VS + t) * VD + h * VDH;
#pragma unroll
    for (int d = 0; d < 64; ++d) op[d] += acc[d] * inv;
  }
}

// ---------------------------------------------------------------- MFMA GEMM
// C[M,N] = A[M,K](fp16) @ Bt[N,K](fp16)^T + bias
// EPI: 0 = store fp32 (REMAP optional), 1 = gelu -> store fp16, 2 = += fp32
#define BM 128
#define BN 128
#define BKK 64
#define LDA 72   // BKK + 8 pad (fp16 elems); 144B row stride, 16B-aligned

template <int EPI, int REMAP>
__global__ __launch_bounds__(256) void gemm_h(
    const unsigned short* __restrict__ A,
    const unsigned short* __restrict__ Bt,
    const float* __restrict__ bias, float* __restrict__ C,
    int M, int N, int K) {
  __shared__ unsigned short As[BM * LDA];
  __shared__ unsigned short Bs[BN * LDA];
  int t = threadIdx.x;
  int bm = blockIdx.y * BM, bn = blockIdx.x * BN;
  int lane = t & 63, wv = t >> 6;
  int wm = (wv & 1) * 64, wn = (wv >> 1) * 64;
  int l15 = lane & 15, l4 = lane >> 4;
  f32x4 acc[4][4] = {};
  int srow = t >> 3;          // 0..31
  int scol = (t & 7) * 8;     // 0..56 (fp16 elems, 16B chunks)
  for (int k0 = 0; k0 < K; k0 += BKK) {
#pragma unroll
    for (int p = 0; p < 4; ++p) {
      int row = p * 32 + srow;
      int grow = bm + row;
      uint4 val = make_uint4(0u, 0u, 0u, 0u);
      if (grow < M) val = *(const uint4*)(A + (size_t)grow * K + k0 + scol);
      *(uint4*)(&As[row * LDA + scol]) = val;
    }
#pragma unroll
    for (int p = 0; p < 4; ++p) {
      int row = p * 32 + srow;
      uint4 val = *(const uint4*)(Bt + (size_t)(bn + row) * K + k0 + scol);
      *(uint4*)(&Bs[row * LDA + scol]) = val;
    }
    __syncthreads();
#pragma unroll
    for (int kk = 0; kk < BKK; kk += 32) {
      half8 af[4], bf[4];
#pragma unroll
      for (int i = 0; i < 4; ++i)
        af[i] = *(const half8*)(&As[(wm + i * 16 + l15) * LDA + kk + l4 * 8]);
#pragma unroll
      for (int j = 0; j < 4; ++j)
        bf[j] = *(const half8*)(&Bs[(wn + j * 16 + l15) * LDA + kk + l4 * 8]);
#pragma unroll
      for (int i = 0; i < 4; ++i)
#pragma unroll
        for (int j = 0; j < 4; ++j)
          acc[i][j] = __builtin_amdgcn_mfma_f32_16x16x32_f16(
              af[i], bf[j], acc[i][j], 0, 0, 0);
    }
    __syncthreads();
  }
#pragma unroll
  for (int i = 0; i < 4; ++i) {
#pragma unroll
    for (int j = 0; j < 4; ++j) {
#pragma unroll
      for (int r = 0; r < 4; ++r) {
        int row = bm + wm + i * 16 + l4 * 4 + r;
        int col = bn + wn + j * 16 + l15;
        if (row < M) {
          float val = acc[i][j][r] + bias[col];
          if (EPI == 0) {
            int crow = REMAP ? (row + row / 196 + 1) : row;
            C[(size_t)crow * N + col] = val;
          } else if (EPI == 1) {
            val = 0.5f * val * (1.0f + erff(val * 0.70710678118654752440f));
            ((unsigned short*)C)[(size_t)row * N + col] = f2h(val);
          } else {
            C[(size_t)row * N + col] += val;
          }
        }
      }
    }
  }
}

// ---------------------------------------------------------------- classifier
__global__ __launch_bounds__(256) void cls_kernel(
    const float* __restrict__ out_act, const float* __restrict__ Wc,
    const float* __restrict__ bc, float* __restrict__ y) {
  int b = blockIdx.x;
  int t = threadIdx.x;
  __shared__ float xs[768];
  __shared__ float logit[VOUT];
  __shared__ float red[10];
  const float* xr = out_act + (size_t)b * VS * VD;  // cls token row
  xs[t] = xr[t]; xs[t + 256] = xr[t + 256]; xs[t + 512] = xr[t + 512];
  __syncthreads();
  for (int j0 = 0; j0 < VOUT; j0 += 256) {
    int j = j0 + t;
    if (j < VOUT) {
      float acc = bc[j];
      for (int d = 0; d < VD; d++) acc += xs[d] * Wc[(size_t)d * VOUT + j];
      logit[j] = acc;
    }
  }
  __syncthreads();
  float m = -1e30f;
  for (int j = t; j < VOUT; j += 256) m = fmaxf(m, logit[j]);
#pragma unroll
  for (int off = 32; off; off >>= 1) m = fmaxf(m, __shfl_down(m, off));
  if ((t & 63) == 0) red[t >> 6] = m;
  __syncthreads();
  if (t == 0) red[8] = fmaxf(fmaxf(red[0], red[1]), fmaxf(red[2], red[3]));
  __syncthreads();
  float M = red[8];
  float s = 0.f;
  for (int j = t; j < VOUT; j += 256) {
    float e = expf(logit[j] - M);
    logit[j] = e;
    s += e;
  }
#pragma unroll
  for (int off = 32; off; off >>= 1) s += __shfl_down(s, off);
  if ((t & 63) == 0) red[4 + (t >> 6)] = s;
  __syncthreads();
  if (t == 0) red[9] = red[4] + red[5] + red[6] + red[7];
  __syncthreads();
  float inv = 1.0f / red[9];
  for (int j = t; j < VOUT; j += 256) y[(size_t)b * VOUT + j] = logit[j] * inv;
}

// ---------------------------------------------------------------- launch
extern "C" void kernel_launch(void* const* d_in, const int* in_sizes, int n_in,
                              void* d_out, int out_size, void* d_ws, size_t ws_size,
                              hipStream_t stream) {
  const float* x      = (const float*)d_in[0];
  const float* cls    = (const float*)d_in[1];
  const float* pos    = (const float*)d_in[2];
  const float* Wmap   = (const float*)d_in[3];
  const float* bmap   = (const float*)d_in[4];
  const float* ln1_g  = (const float*)d_in[5];
  const float* ln1_b  = (const float*)d_in[6];
  const float* Wq     = (const float*)d_in[7];
  const float* bq     = (const float*)d_in[8];
  const float* Wk     = (const float*)d_in[9];
  const float* bk     = (const float*)d_in[10];
  const float* Wv     = (const float*)d_in[11];
  const float* bv     = (const float*)d_in[12];
  const float* ln2_g  = (const float*)d_in[13];
  const float* ln2_b  = (const float*)d_in[14];
  const float* W1     = (const float*)d_in[15];
  const float* b1     = (const float*)d_in[16];
  const float* W2     = (const float*)d_in[17];
  const float* b2     = (const float*)d_in[18];
  const float* Wc     = (const float*)d_in[19];
  const float* bc     = (const float*)d_in[20];
  float* yout = (float*)d_out;

  const size_t nBS  = (size_t)VB * VS;          // 6304
  const size_t nBSD = nBS * VD;                 // 4,841,472
  char* base = (char*)d_ws;
  size_t off = 0;
  float* out_act = (float*)(base + off);      off += nBSD * 4;
  unsigned short* xnb = (unsigned short*)(base + off); off += nBSD * 2;
  float* qb = (float*)(base + off);           off += nBSD * 4;
  float* kb = (float*)(base + off);           off += nBSD * 4;
  float* vb = (float*)(base + off);           off += nBSD * 4;
  unsigned short* hbuf = (unsigned short*)(base + off); off += nBS * VMLP * 2;
  unsigned short* wmapT = (unsigned short*)(base + off); off += (size_t)VD * VD * 2;
  unsigned short* w1T = (unsigned short*)(base + off);   off += (size_t)VL * VMLP * VD * 2;
  unsigned short* w2T = (unsigned short*)(base + off);   off += (size_t)VL * VD * VMLP * 2;
  unsigned short* wqkv = (unsigned short*)(base + off);  off += (size_t)VL * VNH * 192 * 64 * 2;

  // weight transposes / packs (fp32 -> fp16)
  transpose_kernel<<<dim3(12, 12, 1), 256, 0, stream>>>(Wmap, wmapT, VD, VD);
  transpose_kernel<<<dim3(48, 12, VL), 256, 0, stream>>>(W1, w1T, VD, VMLP);
  transpose_kernel<<<dim3(12, 48, VL), 256, 0, stream>>>(W2, w2T, VMLP, VD);
  pack_qkv_kernel<<<(VL * VNH * 192 * 64) / 256, 256, 0, stream>>>(Wq, Wk, Wv, wqkv);

  // patchify (fp16 patches into hbuf)
  patchify_kernel<<<VB * VNPAT, 256, 0, stream>>>(x, hbuf);
  // embed GEMM: out rows [b*197 + 1 + p]
  gemm_h<0, 1><<<dim3(VD / BN, (VB * VNPAT) / BM), 256, 0, stream>>>(
      hbuf, wmapT, bmap, out_act, VB * VNPAT, VD, VD);
  // cls token + positional embedding
  addpos_kernel<<<(int)nBS, 256, 0, stream>>>(cls, pos, out_act);

  for (int l = 0; l < VL; l++) {
    ln_kernel<<<(int)nBS, 256, 0, stream>>>(out_act, xnb,
                                            ln1_g + (size_t)l * VD,
                                            ln1_b + (size_t)l * VD);
    qkv_gemm<<<dim3(50, VNH), 256, 0, stream>>>(
        xnb, wqkv + (size_t)l * VNH * 192 * 64,
        bq + (size_t)l * VNH * VDH, bk + (size_t)l * VNH * VDH,
        bv + (size_t)l * VNH * VDH, qb, kb, vb);
    attn_kernel<<<VB * VNH, 256, 0, stream>>>(qb, kb, vb, out_act);
    ln_kernel<<<(int)nBS, 256, 0, stream>>>(out_act, xnb,
                                            ln2_g + (size_t)l * VD,
                                            ln2_b + (size_t)l * VD);
    // MLP1: h = gelu(xn @ W1 + b1) -> fp16 hbuf
    gemm_h<1, 0><<<dim3(VMLP / BN, ((int)nBS + BM - 1) / BM), 256, 0, stream>>>(
        xnb, w1T + (size_t)l * VMLP * VD, b1 + (size_t)l * VMLP,
        (float*)hbuf, (int)nBS, VMLP, VD);
    // MLP2: out += h @ W2 + b2
    gemm_h<2, 0><<<dim3(VD / BN, ((int)nBS + BM - 1) / BM), 256, 0, stream>>>(
        hbuf, w2T + (size_t)l * VD * VMLP, b2 + (size_t)l * VD,
        out_act, (int)nBS, VD, VMLP);
  }
  cls_kernel<<<VB, 256, 0, stream>>>(out_act, Wc, bc, yout);
}

// Round 4
// 4290.050 us; speedup vs baseline: 5.8302x; 1.2277x over previous
//
#include <hip/hip_runtime.h>
#include <hip/hip_bf16.h>
#include <math.h>

// ViT-Base forward: B=32, C=3, IMG=224, NP=14, PS=16, IN_DIM=768, D=768,
// NH=12, DH=64, L=12, MLP=3072, OUT=1000, S=197
#define VB   32
#define VD   768
#define VNH  12
#define VDH  64
#define VL   12
#define VMLP 3072
#define VOUT 1000
#define VS   197
#define VNPAT 196

typedef _Float16 half8 __attribute__((ext_vector_type(8)));
typedef _Float16 half4 __attribute__((ext_vector_type(4)));
typedef float f32x4 __attribute__((ext_vector_type(4)));

static __device__ __forceinline__ unsigned short f2h(float f) {
  _Float16 h = (_Float16)f;
  return __builtin_bit_cast(unsigned short, h);
}
static __device__ __forceinline__ float h2f(unsigned short u) {
  return (float)__builtin_bit_cast(_Float16, u);
}

// ---------------------------------------------------------------- patchify
__global__ __launch_bounds__(256) void patchify_kernel(
    const float* __restrict__ x, unsigned short* __restrict__ P) {
  int bp = blockIdx.x;                 // b*196 + p
  int b = bp / VNPAT, p = bp - b * VNPAT;
  int py = p / 14, px = p - py * 14;
  int t = threadIdx.x;
  int iy = t >> 4, ix = t & 15;
#pragma unroll
  for (int c = 0; c < 3; c++) {
    float val = x[(((size_t)(b * 3 + c) * 224) + (py * 16 + iy)) * 224 + px * 16 + ix];
    P[(size_t)bp * 768 + c * 256 + t] = f2h(val);
  }
}

// ---------------------------------------------------------------- transpose
// W (fp32, K x N, layer-strided) -> WT (fp16, N x K)
__global__ __launch_bounds__(256) void transpose_kernel(
    const float* __restrict__ W, unsigned short* __restrict__ WT,
    int K, int N) {
  __shared__ float ts[64][65];
  int n0 = blockIdx.x * 64, k0 = blockIdx.y * 64;
  const float* Wl = W + (size_t)blockIdx.z * K * N;
  unsigned short* WTl = WT + (size_t)blockIdx.z * K * N;
  int t = threadIdx.x;
  int r = t >> 4, c4 = (t & 15) * 4;
#pragma unroll
  for (int p = 0; p < 4; ++p) {
    int row = p * 16 + r;
    float4 v = *(const float4*)(Wl + (size_t)(k0 + row) * N + n0 + c4);
    ts[row][c4 + 0] = v.x; ts[row][c4 + 1] = v.y;
    ts[row][c4 + 2] = v.z; ts[row][c4 + 3] = v.w;
  }
  __syncthreads();
#pragma unroll
  for (int p = 0; p < 4; ++p) {
    int n = p * 16 + r;
    ushort4 o;
    o.x = f2h(ts[c4 + 0][n]);
    o.y = f2h(ts[c4 + 1][n]);
    o.z = f2h(ts[c4 + 2][n]);
    o.w = f2h(ts[c4 + 3][n]);
    *(ushort4*)(WTl + (size_t)(n0 + n) * K + k0 + c4) = o;
  }
}

// ---------------------------------------------------------------- pack QKV
// Wp[l][h][n][d] fp16, n in 0..191: 0-63 = Wq[e][d], 64-127 = Wk, 128-191 = Wv
__global__ __launch_bounds__(256) void pack_qkv_kernel(
    const float* __restrict__ Wq, const float* __restrict__ Wk,
    const float* __restrict__ Wv, unsigned short* __restrict__ Wp) {
  size_t idx = (size_t)blockIdx.x * 256 + threadIdx.x;  // < 12*12*192*64
  int d = idx & 63;
  size_t r = idx >> 6;            // lh*192 + n
  int n = (int)(r % 192);
  size_t lh = r / 192;            // l*12 + h
  int which = n >> 6, e = n & 63;
  const float* W = which == 0 ? Wq : which == 1 ? Wk : Wv;
  Wp[idx] = f2h(W[(lh * 64 + e) * 64 + d]);
}

// ---------------------------------------------------------------- cls + pos
__global__ __launch_bounds__(256) void addpos_kernel(
    const float* __restrict__ cls, const float* __restrict__ pos,
    float* __restrict__ out) {
  int bs = blockIdx.x;                 // b*197 + s
  int s = bs % VS;
  int t = threadIdx.x;
  size_t o = (size_t)bs * VD;
#pragma unroll
  for (int j = 0; j < 3; j++) {
    int d = j * 256 + t;
    if (s == 0) out[o + d] = cls[d] + pos[d];
    else        out[o + d] += pos[(size_t)s * VD + d];
  }
}

// ---------------------------------------------------------------- layernorm
// fp32 in -> fp16 out
__global__ __launch_bounds__(256) void ln_kernel(
    const float* __restrict__ x, unsigned short* __restrict__ y,
    const float* __restrict__ g, const float* __restrict__ b) {
  int row = blockIdx.x;
  int t = threadIdx.x;
  const float* xr = x + (size_t)row * VD;
  float v0 = xr[t], v1 = xr[t + 256], v2 = xr[t + 512];
  float s = v0 + v1 + v2;
  float ss = v0 * v0 + v1 * v1 + v2 * v2;
#pragma unroll
  for (int off = 32; off; off >>= 1) {
    s  += __shfl_down(s, off);
    ss += __shfl_down(ss, off);
  }
  __shared__ float red[10];
  int wid = t >> 6, lane = t & 63;
  if (lane == 0) { red[wid] = s; red[4 + wid] = ss; }
  __syncthreads();
  if (t == 0) {
    float S  = red[0] + red[1] + red[2] + red[3];
    float SS = red[4] + red[5] + red[6] + red[7];
    float mu = S * (1.0f / VD);
    float var = SS * (1.0f / VD) - mu * mu;
    red[8] = mu;
    red[9] = rsqrtf(var + 1e-5f);
  }
  __syncthreads();
  float mu = red[8], rs = red[9];
  unsigned short* yr = y + (size_t)row * VD;
  yr[t]       = f2h((v0 - mu) * rs * g[t]       + b[t]);
  yr[t + 256] = f2h((v1 - mu) * rs * g[t + 256] + b[t + 256]);
  yr[t + 512] = f2h((v2 - mu) * rs * g[t + 512] + b[t + 512]);
}

// ---------------------------------------------------------------- QKV GEMM
// per head h: C[6304, 192] = xn[:, h*64:(h+1)*64] @ Wp[h]^T (+bias)
// out: qh/kh fp16 [bh][s][64]; vt fp16 [bh][d][208] (transposed)
__global__ __launch_bounds__(256) void qkv_gemm(
    const unsigned short* __restrict__ xn,     // [6304, 768] fp16
    const unsigned short* __restrict__ Wp,     // [12][192][64] fp16 (layer base)
    const float* __restrict__ bq, const float* __restrict__ bk,
    const float* __restrict__ bv,              // [12][64] each (layer base)
    unsigned short* __restrict__ qh, unsigned short* __restrict__ kh,
    unsigned short* __restrict__ vt) {
  __shared__ unsigned short As[128 * 72];
  __shared__ unsigned short Bs[192 * 72];
  int h = blockIdx.y;
  int bm = blockIdx.x * 128;
  int t = threadIdx.x;
  int srow = t >> 3;          // 0..31
  int scol = (t & 7) * 8;     // 0..56
#pragma unroll
  for (int p = 0; p < 4; ++p) {
    int row = p * 32 + srow;
    int grow = bm + row;
    uint4 val = make_uint4(0u, 0u, 0u, 0u);
    if (grow < VB * VS)
      val = *(const uint4*)(xn + (size_t)grow * VD + h * 64 + scol);
    *(uint4*)(&As[row * 72 + scol]) = val;
  }
#pragma unroll
  for (int p = 0; p < 6; ++p) {
    int row = p * 32 + srow;
    uint4 val = *(const uint4*)(Wp + ((size_t)h * 192 + row) * 64 + scol);
    *(uint4*)(&Bs[row * 72 + scol]) = val;
  }
  __syncthreads();
  int lane = t & 63, wv = t >> 6;
  int wm = (wv & 1) * 64, wn = (wv >> 1) * 96;
  int l15 = lane & 15, l4 = lane >> 4;
  f32x4 acc[4][6] = {};
#pragma unroll
  for (int kk = 0; kk < 64; kk += 32) {
    half8 af[4], bf[6];
#pragma unroll
    for (int i = 0; i < 4; ++i)
      af[i] = *(const half8*)(&As[(wm + i * 16 + l15) * 72 + kk + l4 * 8]);
#pragma unroll
    for (int j = 0; j < 6; ++j)
      bf[j] = *(const half8*)(&Bs[(wn + j * 16 + l15) * 72 + kk + l4 * 8]);
#pragma unroll
    for (int i = 0; i < 4; ++i)
#pragma unroll
      for (int j = 0; j < 6; ++j)
        acc[i][j] = __builtin_amdgcn_mfma_f32_16x16x32_f16(
            af[i], bf[j], acc[i][j], 0, 0, 0);
  }
#pragma unroll
  for (int j = 0; j < 6; ++j) {
    int n = wn + j * 16 + l15;           // 0..191
    int which = n >> 6, e = n & 63;
    const float* bias = which == 0 ? bq : which == 1 ? bk : bv;
    float bval = bias[h * 64 + e];
#pragma unroll
    for (int i = 0; i < 4; ++i) {
#pragma unroll
      for (int r = 0; r < 4; ++r) {
        int tok = bm + wm + i * 16 + l4 * 4 + r;   // token index
        if (tok < VB * VS) {
          int b = tok / VS, s = tok - b * VS;
          size_t bh = (size_t)b * VNH + h;
          unsigned short val = f2h(acc[i][j][r] + bval);
          if (which == 0)      qh[(bh * VS + s) * 64 + e] = val;
          else if (which == 1) kh[(bh * VS + s) * 64 + e] = val;
          else                 vt[(bh * 64 + e) * 208 + s] = val;
        }
      }
    }
  }
}

// ---------------------------------------------------------------- attention
// MFMA flash-ish: grid (bh, qtile). 4 waves x 16 q-rows each.
// S = Q@K^T (16x16x32, operands straight from global), softmax in C-layout
// via shfl_xor, P -> per-wave LDS (stride 212), PV via 16x16x16, residual add.
#define PSTR 212
__global__ __launch_bounds__(256) void attn_mfma(
    const unsigned short* __restrict__ qh,   // [384*197][64] fp16
    const unsigned short* __restrict__ kh,   // [384*197][64] fp16
    const unsigned short* __restrict__ vt,   // [384*64][208] fp16
    float* __restrict__ out) {
  int bh = blockIdx.x;                 // b*12 + h
  int qt = blockIdx.y;                 // 0..3
  int t = threadIdx.x;
  int w = t >> 6, lane = t & 63;
  int l15 = lane & 15, l4 = lane >> 4;
  __shared__ unsigned short Pl[4][16 * PSTR];

  // Q fragments (A): m = l15 -> qrow, k = l4*8 + 0..7
  int qrow = qt * 64 + w * 16 + l15;
  const unsigned short* qbase = qh + ((size_t)bh * VS) * 64;
  const unsigned short* kbase = kh + ((size_t)bh * VS) * 64;
  half8 qf0 = *(const half8*)(qbase + (size_t)qrow * 64 + l4 * 8);
  half8 qf1 = *(const half8*)(qbase + (size_t)qrow * 64 + 32 + l4 * 8);

  f32x4 S[13];
#pragma unroll
  for (int j = 0; j < 13; ++j) {
    half8 b0 = *(const half8*)(kbase + (size_t)(j * 16 + l15) * 64 + l4 * 8);
    half8 b1 = *(const half8*)(kbase + (size_t)(j * 16 + l15) * 64 + 32 + l4 * 8);
    f32x4 c = {};
    c = __builtin_amdgcn_mfma_f32_16x16x32_f16(qf0, b0, c, 0, 0, 0);
    c = __builtin_amdgcn_mfma_f32_16x16x32_f16(qf1, b1, c, 0, 0, 0);
    S[j] = c;
  }
  // scale + mask (cols >= 197 live in j==12, l15 > 4)
  float m4[4] = {-3.0e38f, -3.0e38f, -3.0e38f, -3.0e38f};
#pragma unroll
  for (int j = 0; j < 13; ++j) {
#pragma unroll
    for (int r = 0; r < 4; ++r) {
      float s = S[j][r] * 0.125f;
      if (j == 12 && l15 > 4) s = -3.0e38f;
      S[j][r] = s;
      m4[r] = fmaxf(m4[r], s);
    }
  }
#pragma unroll
  for (int off = 1; off < 16; off <<= 1) {
#pragma unroll
    for (int r = 0; r < 4; ++r) m4[r] = fmaxf(m4[r], __shfl_xor(m4[r], off));
  }
  float ls[4] = {0.f, 0.f, 0.f, 0.f};
#pragma unroll
  for (int j = 0; j < 13; ++j) {
#pragma unroll
    for (int r = 0; r < 4; ++r) {
      float p = __expf(S[j][r] - m4[r]);
      S[j][r] = p;
      ls[r] += p;
    }
  }
#pragma unroll
  for (int off = 1; off < 16; off <<= 1) {
#pragma unroll
    for (int r = 0; r < 4; ++r) ls[r] += __shfl_xor(ls[r], off);
  }
  // P -> LDS fp16, row = q within wave tile (l4*4+r), col = key
  unsigned short* Pw = &Pl[w][0];
#pragma unroll
  for (int j = 0; j < 13; ++j) {
#pragma unroll
    for (int r = 0; r < 4; ++r)
      Pw[(l4 * 4 + r) * PSTR + j * 16 + l15] = f2h(S[j][r]);
  }
  // PV: O[16 q x 64 d], A = P from LDS, B = vt from global
  const unsigned short* vbase = vt + (size_t)bh * 64 * 208;
  f32x4 O[4] = {};
#pragma unroll
  for (int jk = 0; jk < 13; ++jk) {
    half4 a = *(const half4*)(Pw + l15 * PSTR + jk * 16 + l4 * 4);
#pragma unroll
    for (int jn = 0; jn < 4; ++jn) {
      half4 b = *(const half4*)(vbase + (size_t)(jn * 16 + l15) * 208 + jk * 16 + l4 * 4);
      O[jn] = __builtin_amdgcn_mfma_f32_16x16x16f16(a, b, O[jn], 0, 0, 0);
    }
  }
  // epilogue: /= l, residual add
  int b = bh / VNH, h = bh - (bh / VNH) * VNH;
  float linv[4];
#pragma unroll
  for (int r = 0; r < 4; ++r) linv[r] = 1.0f / ls[r];
#pragma unroll
  for (int r = 0; r < 4; ++r) {
    int qr = qt * 64 + w * 16 + l4 * 4 + r;
    if (qr < VS) {
      float* op = out + ((size_t)b * VS + qr) * VD + h * VDH;
#pragma unroll
      for (int jn = 0; jn < 4; ++jn)
        op[jn * 16 + l15] += O[jn][r] * linv[r];
    }
  }
}

// ---------------------------------------------------------------- MFMA GEMM
// C[M,N] = A[M,K](fp16) @ Bt[N,K](fp16)^T + bias
// EPI: 0 = store fp32 (REMAP optional), 1 = gelu -> store fp16, 2 = += fp32
#define BM 128
#define BN 128
#define BKK 64
#define LDA 72   // BKK + 8 pad (fp16 elems)

template <int EPI, int REMAP>
__global__ __launch_bounds__(256) void gemm_h(
    const unsigned short* __restrict__ A,
    const unsigned short* __restrict__ Bt,
    const float* __restrict__ bias, float* __restrict__ C,
    int M, int N, int K) {
  __shared__ unsigned short As[BM * LDA];
  __shared__ unsigned short Bs[BN * LDA];
  int t = threadIdx.x;
  int bm = blockIdx.y * BM, bn = blockIdx.x * BN;
  int lane = t & 63, wv = t >> 6;
  int wm = (wv & 1) * 64, wn = (wv >> 1) * 64;
  int l15 = lane & 15, l4 = lane >> 4;
  f32x4 acc[4][4] = {};
  int srow = t >> 3;          // 0..31
  int scol = (t & 7) * 8;     // 0..56 (fp16 elems, 16B chunks)
  for (int k0 = 0; k0 < K; k0 += BKK) {
#pragma unroll
    for (int p = 0; p < 4; ++p) {
      int row = p * 32 + srow;
      int grow = bm + row;
      uint4 val = make_uint4(0u, 0u, 0u, 0u);
      if (grow < M) val = *(const uint4*)(A + (size_t)grow * K + k0 + scol);
      *(uint4*)(&As[row * LDA + scol]) = val;
    }
#pragma unroll
    for (int p = 0; p < 4; ++p) {
      int row = p * 32 + srow;
      uint4 val = *(const uint4*)(Bt + (size_t)(bn + row) * K + k0 + scol);
      *(uint4*)(&Bs[row * LDA + scol]) = val;
    }
    __syncthreads();
#pragma unroll
    for (int kk = 0; kk < BKK; kk += 32) {
      half8 af[4], bf[4];
#pragma unroll
      for (int i = 0; i < 4; ++i)
        af[i] = *(const half8*)(&As[(wm + i * 16 + l15) * LDA + kk + l4 * 8]);
#pragma unroll
      for (int j = 0; j < 4; ++j)
        bf[j] = *(const half8*)(&Bs[(wn + j * 16 + l15) * LDA + kk + l4 * 8]);
#pragma unroll
      for (int i = 0; i < 4; ++i)
#pragma unroll
        for (int j = 0; j < 4; ++j)
          acc[i][j] = __builtin_amdgcn_mfma_f32_16x16x32_f16(
              af[i], bf[j], acc[i][j], 0, 0, 0);
    }
    __syncthreads();
  }
#pragma unroll
  for (int i = 0; i < 4; ++i) {
#pragma unroll
    for (int j = 0; j < 4; ++j) {
#pragma unroll
      for (int r = 0; r < 4; ++r) {
        int row = bm + wm + i * 16 + l4 * 4 + r;
        int col = bn + wn + j * 16 + l15;
        if (row < M) {
          float val = acc[i][j][r] + bias[col];
          if (EPI == 0) {
            int crow = REMAP ? (row + row / 196 + 1) : row;
            C[(size_t)crow * N + col] = val;
          } else if (EPI == 1) {
            val = 0.5f * val * (1.0f + erff(val * 0.70710678118654752440f));
            ((unsigned short*)C)[(size_t)row * N + col] = f2h(val);
          } else {
            C[(size_t)row * N + col] += val;
          }
        }
      }
    }
  }
}

// ---------------------------------------------------------------- classifier
__global__ __launch_bounds__(256) void cls_kernel(
    const float* __restrict__ out_act, const float* __restrict__ Wc,
    const float* __restrict__ bc, float* __restrict__ y) {
  int b = blockIdx.x;
  int t = threadIdx.x;
  __shared__ float xs[768];
  __shared__ float logit[VOUT];
  __shared__ float red[10];
  const float* xr = out_act + (size_t)b * VS * VD;  // cls token row
  xs[t] = xr[t]; xs[t + 256] = xr[t + 256]; xs[t + 512] = xr[t + 512];
  __syncthreads();
  for (int j0 = 0; j0 < VOUT; j0 += 256) {
    int j = j0 + t;
    if (j < VOUT) {
      float acc = bc[j];
      for (int d = 0; d < VD; d++) acc += xs[d] * Wc[(size_t)d * VOUT + j];
      logit[j] = acc;
    }
  }
  __syncthreads();
  float m = -1e30f;
  for (int j = t; j < VOUT; j += 256) m = fmaxf(m, logit[j]);
#pragma unroll
  for (int off = 32; off; off >>= 1) m = fmaxf(m, __shfl_down(m, off));
  if ((t & 63) == 0) red[t >> 6] = m;
  __syncthreads();
  if (t == 0) red[8] = fmaxf(fmaxf(red[0], red[1]), fmaxf(red[2], red[3]));
  __syncthreads();
  float M = red[8];
  float s = 0.f;
  for (int j = t; j < VOUT; j += 256) {
    float e = expf(logit[j] - M);
    logit[j] = e;
    s += e;
  }
#pragma unroll
  for (int off = 32; off; off >>= 1) s += __shfl_down(s, off);
  if ((t & 63) == 0) red[4 + (t >> 6)] = s;
  __syncthreads();
  if (t == 0) red[9] = red[4] + red[5] + red[6] + red[7];
  __syncthreads();
  float inv = 1.0f / red[9];
  for (int j = t; j < VOUT; j += 256) y[(size_t)b * VOUT + j] = logit[j] * inv;
}

// ---------------------------------------------------------------- launch
extern "C" void kernel_launch(void* const* d_in, const int* in_sizes, int n_in,
                              void* d_out, int out_size, void* d_ws, size_t ws_size,
                              hipStream_t stream) {
  const float* x      = (const float*)d_in[0];
  const float* cls    = (const float*)d_in[1];
  const float* pos    = (const float*)d_in[2];
  const float* Wmap   = (const float*)d_in[3];
  const float* bmap   = (const float*)d_in[4];
  const float* ln1_g  = (const float*)d_in[5];
  const float* ln1_b  = (const float*)d_in[6];
  const float* Wq     = (const float*)d_in[7];
  const float* bq     = (const float*)d_in[8];
  const float* Wk     = (const float*)d_in[9];
  const float* bk     = (const float*)d_in[10];
  const float* Wv     = (const float*)d_in[11];
  const float* bv     = (const float*)d_in[12];
  const float* ln2_g  = (const float*)d_in[13];
  const float* ln2_b  = (const float*)d_in[14];
  const float* W1     = (const float*)d_in[15];
  const float* b1     = (const float*)d_in[16];
  const float* W2     = (const float*)d_in[17];
  const float* b2     = (const float*)d_in[18];
  const float* Wc     = (const float*)d_in[19];
  const float* bc     = (const float*)d_in[20];
  float* yout = (float*)d_out;

  const size_t nBS  = (size_t)VB * VS;          // 6304
  const size_t nBSD = nBS * VD;                 // 4,841,472
  const size_t nQK  = (size_t)VB * VNH * VS * 64;   // 4,841,472
  char* base = (char*)d_ws;
  size_t off = 0;
  float* out_act = (float*)(base + off);      off += nBSD * 4;
  unsigned short* xnb = (unsigned short*)(base + off); off += nBSD * 2;
  unsigned short* qhb = (unsigned short*)(base + off); off += nQK * 2 + 65536;
  unsigned short* khb = (unsigned short*)(base + off); off += nQK * 2 + 65536;
  unsigned short* vtb = (unsigned short*)(base + off); off += (size_t)VB * VNH * 64 * 208 * 2;
  unsigned short* hbuf = (unsigned short*)(base + off); off += nBS * VMLP * 2;
  unsigned short* wmapT = (unsigned short*)(base + off); off += (size_t)VD * VD * 2;
  unsigned short* w1T = (unsigned short*)(base + off);   off += (size_t)VL * VMLP * VD * 2;
  unsigned short* w2T = (unsigned short*)(base + off);   off += (size_t)VL * VD * VMLP * 2;
  unsigned short* wqkv = (unsigned short*)(base + off);  off += (size_t)VL * VNH * 192 * 64 * 2;

  // weight transposes / packs (fp32 -> fp16)
  transpose_kernel<<<dim3(12, 12, 1), 256, 0, stream>>>(Wmap, wmapT, VD, VD);
  transpose_kernel<<<dim3(48, 12, VL), 256, 0, stream>>>(W1, w1T, VD, VMLP);
  transpose_kernel<<<dim3(12, 48, VL), 256, 0, stream>>>(W2, w2T, VMLP, VD);
  pack_qkv_kernel<<<(VL * VNH * 192 * 64) / 256, 256, 0, stream>>>(Wq, Wk, Wv, wqkv);

  // patchify (fp16 patches into hbuf)
  patchify_kernel<<<VB * VNPAT, 256, 0, stream>>>(x, hbuf);
  // embed GEMM: out rows [b*197 + 1 + p]
  gemm_h<0, 1><<<dim3(VD / BN, (VB * VNPAT) / BM), 256, 0, stream>>>(
      hbuf, wmapT, bmap, out_act, VB * VNPAT, VD, VD);
  // cls token + positional embedding
  addpos_kernel<<<(int)nBS, 256, 0, stream>>>(cls, pos, out_act);

  for (int l = 0; l < VL; l++) {
    ln_kernel<<<(int)nBS, 256, 0, stream>>>(out_act, xnb,
                                            ln1_g + (size_t)l * VD,
                                            ln1_b + (size_t)l * VD);
    qkv_gemm<<<dim3(50, VNH), 256, 0, stream>>>(
        xnb, wqkv + (size_t)l * VNH * 192 * 64,
        bq + (size_t)l * VNH * VDH, bk + (size_t)l * VNH * VDH,
        bv + (size_t)l * VNH * VDH, qhb, khb, vtb);
    attn_mfma<<<dim3(VB * VNH, 4), 256, 0, stream>>>(qhb, khb, vtb, out_act);
    ln_kernel<<<(int)nBS, 256, 0, stream>>>(out_act, xnb,
                                            ln2_g + (size_t)l * VD,
                                            ln2_b + (size_t)l * VD);
    // MLP1: h = gelu(xn @ W1 + b1) -> fp16 hbuf
    gemm_h<1, 0><<<dim3(VMLP / BN, ((int)nBS + BM - 1) / BM), 256, 0, stream>>>(
        xnb, w1T + (size_t)l * VMLP * VD, b1 + (size_t)l * VMLP,
        (float*)hbuf, (int)nBS, VMLP, VD);
    // MLP2: out += h @ W2 + b2
    gemm_h<2, 0><<<dim3(VD / BN, ((int)nBS + BM - 1) / BM), 256, 0, stream>>>(
        hbuf, w2T + (size_t)l * VD * VMLP, b2 + (size_t)l * VD,
        out_act, (int)nBS, VD, VMLP);
  }
  cls_kernel<<<VB, 256, 0, stream>>>(out_act, Wc, bc, yout);
}

// Round 5
// 4070.693 us; speedup vs baseline: 6.1443x; 1.0539x over previous
//
#include <hip/hip_runtime.h>
#include <hip/hip_bf16.h>
#include <math.h>

// ViT-Base forward: B=32, C=3, IMG=224, NP=14, PS=16, IN_DIM=768, D=768,
// NH=12, DH=64, L=12, MLP=3072, OUT=1000, S=197
#define VB   32
#define VD   768
#define VNH  12
#define VDH  64
#define VL   12
#define VMLP 3072
#define VOUT 1000
#define VS   197
#define VNPAT 196

typedef _Float16 half8 __attribute__((ext_vector_type(8)));
typedef _Float16 half4 __attribute__((ext_vector_type(4)));
typedef float f32x4 __attribute__((ext_vector_type(4)));

static __device__ __forceinline__ unsigned short f2h(float f) {
  _Float16 h = (_Float16)f;
  return __builtin_bit_cast(unsigned short, h);
}
static __device__ __forceinline__ float h2f(unsigned short u) {
  return (float)__builtin_bit_cast(_Float16, u);
}

// async global->LDS, 16B per lane; LDS dest = wave-uniform base + lane*16
static __device__ __forceinline__ void gload_lds16(const void* g, void* l) {
  __builtin_amdgcn_global_load_lds(
      (const __attribute__((address_space(1))) unsigned int*)g,
      (__attribute__((address_space(3))) unsigned int*)l, 16, 0, 0);
}

// ---------------------------------------------------------------- patchify
__global__ __launch_bounds__(256) void patchify_kernel(
    const float* __restrict__ x, unsigned short* __restrict__ P) {
  int bp = blockIdx.x;                 // b*196 + p
  int b = bp / VNPAT, p = bp - b * VNPAT;
  int py = p / 14, px = p - py * 14;
  int t = threadIdx.x;
  int iy = t >> 4, ix = t & 15;
#pragma unroll
  for (int c = 0; c < 3; c++) {
    float val = x[(((size_t)(b * 3 + c) * 224) + (py * 16 + iy)) * 224 + px * 16 + ix];
    P[(size_t)bp * 768 + c * 256 + t] = f2h(val);
  }
}

// ---------------------------------------------------------------- transpose
// W (fp32, K x N, layer-strided) -> WT (fp16, N x K)
__global__ __launch_bounds__(256) void transpose_kernel(
    const float* __restrict__ W, unsigned short* __restrict__ WT,
    int K, int N) {
  __shared__ float ts[64][65];
  int n0 = blockIdx.x * 64, k0 = blockIdx.y * 64;
  const float* Wl = W + (size_t)blockIdx.z * K * N;
  unsigned short* WTl = WT + (size_t)blockIdx.z * K * N;
  int t = threadIdx.x;
  int r = t >> 4, c4 = (t & 15) * 4;
#pragma unroll
  for (int p = 0; p < 4; ++p) {
    int row = p * 16 + r;
    float4 v = *(const float4*)(Wl + (size_t)(k0 + row) * N + n0 + c4);
    ts[row][c4 + 0] = v.x; ts[row][c4 + 1] = v.y;
    ts[row][c4 + 2] = v.z; ts[row][c4 + 3] = v.w;
  }
  __syncthreads();
#pragma unroll
  for (int p = 0; p < 4; ++p) {
    int n = p * 16 + r;
    ushort4 o;
    o.x = f2h(ts[c4 + 0][n]);
    o.y = f2h(ts[c4 + 1][n]);
    o.z = f2h(ts[c4 + 2][n]);
    o.w = f2h(ts[c4 + 3][n]);
    *(ushort4*)(WTl + (size_t)(n0 + n) * K + k0 + c4) = o;
  }
}

// ---------------------------------------------------------------- pack QKV
__global__ __launch_bounds__(256) void pack_qkv_kernel(
    const float* __restrict__ Wq, const float* __restrict__ Wk,
    const float* __restrict__ Wv, unsigned short* __restrict__ Wp) {
  size_t idx = (size_t)blockIdx.x * 256 + threadIdx.x;  // < 12*12*192*64
  int d = idx & 63;
  size_t r = idx >> 6;            // lh*192 + n
  int n = (int)(r % 192);
  size_t lh = r / 192;            // l*12 + h
  int which = n >> 6, e = n & 63;
  const float* W = which == 0 ? Wq : which == 1 ? Wk : Wv;
  Wp[idx] = f2h(W[(lh * 64 + e) * 64 + d]);
}

// ---------------------------------------------------------------- cls + pos
__global__ __launch_bounds__(256) void addpos_kernel(
    const float* __restrict__ cls, const float* __restrict__ pos,
    float* __restrict__ out) {
  int bs = blockIdx.x;                 // b*197 + s
  int s = bs % VS;
  int t = threadIdx.x;
  size_t o = (size_t)bs * VD;
#pragma unroll
  for (int j = 0; j < 3; j++) {
    int d = j * 256 + t;
    if (s == 0) out[o + d] = cls[d] + pos[d];
    else        out[o + d] += pos[(size_t)s * VD + d];
  }
}

// ---------------------------------------------------------------- layernorm
// fp32 in -> fp16 out
__global__ __launch_bounds__(256) void ln_kernel(
    const float* __restrict__ x, unsigned short* __restrict__ y,
    const float* __restrict__ g, const float* __restrict__ b) {
  int row = blockIdx.x;
  int t = threadIdx.x;
  const float* xr = x + (size_t)row * VD;
  float v0 = xr[t], v1 = xr[t + 256], v2 = xr[t + 512];
  float s = v0 + v1 + v2;
  float ss = v0 * v0 + v1 * v1 + v2 * v2;
#pragma unroll
  for (int off = 32; off; off >>= 1) {
    s  += __shfl_down(s, off);
    ss += __shfl_down(ss, off);
  }
  __shared__ float red[10];
  int wid = t >> 6, lane = t & 63;
  if (lane == 0) { red[wid] = s; red[4 + wid] = ss; }
  __syncthreads();
  if (t == 0) {
    float S  = red[0] + red[1] + red[2] + red[3];
    float SS = red[4] + red[5] + red[6] + red[7];
    float mu = S * (1.0f / VD);
    float var = SS * (1.0f / VD) - mu * mu;
    red[8] = mu;
    red[9] = rsqrtf(var + 1e-5f);
  }
  __syncthreads();
  float mu = red[8], rs = red[9];
  unsigned short* yr = y + (size_t)row * VD;
  yr[t]       = f2h((v0 - mu) * rs * g[t]       + b[t]);
  yr[t + 256] = f2h((v1 - mu) * rs * g[t + 256] + b[t + 256]);
  yr[t + 512] = f2h((v2 - mu) * rs * g[t + 512] + b[t + 512]);
}

// ---------------------------------------------------------------- QKV GEMM
// per head h: C[6304, 192] = xn[:, h*64:(h+1)*64] @ Wp[h]^T (+bias)
// out: qh/kh fp16 [bh][s][64]; vt fp16 [bh][d][208] (transposed)
__global__ __launch_bounds__(256) void qkv_gemm(
    const unsigned short* __restrict__ xn,     // [6304, 768] fp16
    const unsigned short* __restrict__ Wp,     // [12][192][64] fp16 (layer base)
    const float* __restrict__ bq, const float* __restrict__ bk,
    const float* __restrict__ bv,              // [12][64] each (layer base)
    unsigned short* __restrict__ qh, unsigned short* __restrict__ kh,
    unsigned short* __restrict__ vt) {
  __shared__ unsigned short As[128 * 72];
  __shared__ unsigned short Bs[192 * 72];
  int h = blockIdx.y;
  int bm = blockIdx.x * 128;
  int t = threadIdx.x;
  int srow = t >> 3;          // 0..31
  int scol = (t & 7) * 8;     // 0..56
#pragma unroll
  for (int p = 0; p < 4; ++p) {
    int row = p * 32 + srow;
    int grow = bm + row;
    uint4 val = make_uint4(0u, 0u, 0u, 0u);
    if (grow < VB * VS)
      val = *(const uint4*)(xn + (size_t)grow * VD + h * 64 + scol);
    *(uint4*)(&As[row * 72 + scol]) = val;
  }
#pragma unroll
  for (int p = 0; p < 6; ++p) {
    int row = p * 32 + srow;
    uint4 val = *(const uint4*)(Wp + ((size_t)h * 192 + row) * 64 + scol);
    *(uint4*)(&Bs[row * 72 + scol]) = val;
  }
  __syncthreads();
  int lane = t & 63, wv = t >> 6;
  int wm = (wv & 1) * 64, wn = (wv >> 1) * 96;
  int l15 = lane & 15, l4 = lane >> 4;
  f32x4 acc[4][6] = {};
#pragma unroll
  for (int kk = 0; kk < 64; kk += 32) {
    half8 af[4], bf[6];
#pragma unroll
    for (int i = 0; i < 4; ++i)
      af[i] = *(const half8*)(&As[(wm + i * 16 + l15) * 72 + kk + l4 * 8]);
#pragma unroll
    for (int j = 0; j < 6; ++j)
      bf[j] = *(const half8*)(&Bs[(wn + j * 16 + l15) * 72 + kk + l4 * 8]);
#pragma unroll
    for (int i = 0; i < 4; ++i)
#pragma unroll
      for (int j = 0; j < 6; ++j)
        acc[i][j] = __builtin_amdgcn_mfma_f32_16x16x32_f16(
            af[i], bf[j], acc[i][j], 0, 0, 0);
  }
#pragma unroll
  for (int j = 0; j < 6; ++j) {
    int n = wn + j * 16 + l15;           // 0..191
    int which = n >> 6, e = n & 63;
    const float* bias = which == 0 ? bq : which == 1 ? bk : bv;
    float bval = bias[h * 64 + e];
#pragma unroll
    for (int i = 0; i < 4; ++i) {
#pragma unroll
      for (int r = 0; r < 4; ++r) {
        int tok = bm + wm + i * 16 + l4 * 4 + r;   // token index
        if (tok < VB * VS) {
          int b = tok / VS, s = tok - b * VS;
          size_t bh = (size_t)b * VNH + h;
          unsigned short val = f2h(acc[i][j][r] + bval);
          if (which == 0)      qh[(bh * VS + s) * 64 + e] = val;
          else if (which == 1) kh[(bh * VS + s) * 64 + e] = val;
          else                 vt[(bh * 64 + e) * 208 + s] = val;
        }
      }
    }
  }
}

// zero vt pad columns 197..207 (aliased scratch may hold NaN-pattern fp16)
__global__ __launch_bounds__(256) void vt_ztail(unsigned short* __restrict__ vt) {
  int i = blockIdx.x * 256 + threadIdx.x;   // < 384*64*11
  int c = i % 11;
  int rd = i / 11;                           // bh*64 + d
  vt[(size_t)rd * 208 + 197 + c] = 0;
}

// ---------------------------------------------------------------- attention
// MFMA flash-ish: grid (bh, qtile). 4 waves x 16 q-rows each.
#define PSTR 212
__global__ __launch_bounds__(256) void attn_mfma(
    const unsigned short* __restrict__ qh,   // [384*197][64] fp16
    const unsigned short* __restrict__ kh,   // [384*197][64] fp16
    const unsigned short* __restrict__ vt,   // [384*64][208] fp16
    float* __restrict__ out) {
  int bh = blockIdx.x;                 // b*12 + h
  int qt = blockIdx.y;                 // 0..3
  int t = threadIdx.x;
  int w = t >> 6, lane = t & 63;
  int l15 = lane & 15, l4 = lane >> 4;
  __shared__ unsigned short Pl[4][16 * PSTR];

  int qrow = qt * 64 + w * 16 + l15;
  const unsigned short* qbase = qh + ((size_t)bh * VS) * 64;
  const unsigned short* kbase = kh + ((size_t)bh * VS) * 64;
  half8 qf0 = *(const half8*)(qbase + (size_t)qrow * 64 + l4 * 8);
  half8 qf1 = *(const half8*)(qbase + (size_t)qrow * 64 + 32 + l4 * 8);

  f32x4 S[13];
#pragma unroll
  for (int j = 0; j < 13; ++j) {
    half8 b0 = *(const half8*)(kbase + (size_t)(j * 16 + l15) * 64 + l4 * 8);
    half8 b1 = *(const half8*)(kbase + (size_t)(j * 16 + l15) * 64 + 32 + l4 * 8);
    f32x4 c = {};
    c = __builtin_amdgcn_mfma_f32_16x16x32_f16(qf0, b0, c, 0, 0, 0);
    c = __builtin_amdgcn_mfma_f32_16x16x32_f16(qf1, b1, c, 0, 0, 0);
    S[j] = c;
  }
  float m4[4] = {-3.0e38f, -3.0e38f, -3.0e38f, -3.0e38f};
#pragma unroll
  for (int j = 0; j < 13; ++j) {
#pragma unroll
    for (int r = 0; r < 4; ++r) {
      float s = S[j][r] * 0.125f;
      if (j == 12 && l15 > 4) s = -3.0e38f;
      S[j][r] = s;
      m4[r] = fmaxf(m4[r], s);
    }
  }
#pragma unroll
  for (int off = 1; off < 16; off <<= 1) {
#pragma unroll
    for (int r = 0; r < 4; ++r) m4[r] = fmaxf(m4[r], __shfl_xor(m4[r], off));
  }
  float ls[4] = {0.f, 0.f, 0.f, 0.f};
#pragma unroll
  for (int j = 0; j < 13; ++j) {
#pragma unroll
    for (int r = 0; r < 4; ++r) {
      float p = __expf(S[j][r] - m4[r]);
      S[j][r] = p;
      ls[r] += p;
    }
  }
#pragma unroll
  for (int off = 1; off < 16; off <<= 1) {
#pragma unroll
    for (int r = 0; r < 4; ++r) ls[r] += __shfl_xor(ls[r], off);
  }
  unsigned short* Pw = &Pl[w][0];
#pragma unroll
  for (int j = 0; j < 13; ++j) {
#pragma unroll
    for (int r = 0; r < 4; ++r)
      Pw[(l4 * 4 + r) * PSTR + j * 16 + l15] = f2h(S[j][r]);
  }
  const unsigned short* vbase = vt + (size_t)bh * 64 * 208;
  f32x4 O[4] = {};
#pragma unroll
  for (int jk = 0; jk < 13; ++jk) {
    half4 a = *(const half4*)(Pw + l15 * PSTR + jk * 16 + l4 * 4);
#pragma unroll
    for (int jn = 0; jn < 4; ++jn) {
      half4 b = *(const half4*)(vbase + (size_t)(jn * 16 + l15) * 208 + jk * 16 + l4 * 4);
      O[jn] = __builtin_amdgcn_mfma_f32_16x16x16f16(a, b, O[jn], 0, 0, 0);
    }
  }
  int b = bh / VNH, h = bh - (bh / VNH) * VNH;
  float linv[4];
#pragma unroll
  for (int r = 0; r < 4; ++r) linv[r] = 1.0f / ls[r];
#pragma unroll
  for (int r = 0; r < 4; ++r) {
    int qr = qt * 64 + w * 16 + l4 * 4 + r;
    if (qr < VS) {
      float* op = out + ((size_t)b * VS + qr) * VD + h * VDH;
#pragma unroll
      for (int jn = 0; jn < 4; ++jn)
        op[jn * 16 + l15] += O[jn][r] * linv[r];
    }
  }
}

// ---------------------------------------------------------------- MFMA GEMM
// C[M,N] = A[M,K](fp16) @ Bt[N,K](fp16)^T + bias
// EPI: 0 = store fp32 (REMAP), 1 = gelu -> fp16, 2 = += fp32, 3 = raw fp32
//      partial (split-K; C offset by blockIdx.z*M*N, no bias)
// Staging via global_load_lds width 16 into unpadded [128][64] LDS tiles.
template <int EPI, int REMAP>
__global__ __launch_bounds__(256) void gemm_h(
    const unsigned short* __restrict__ A,
    const unsigned short* __restrict__ Bt,
    const float* __restrict__ bias, float* __restrict__ C,
    int M, int N, int K, int KS) {
  __shared__ unsigned short As[128 * 64];
  __shared__ unsigned short Bs[128 * 64];
  int t = threadIdx.x;
  int bm = blockIdx.y * 128, bn = blockIdx.x * 128;
  int lane = t & 63, w = t >> 6;
  int wm = (w & 1) * 64, wn = (w >> 1) * 64;
  int l15 = lane & 15, l4 = lane >> 4;
  int lrow = lane >> 3, lcol = (lane & 7) * 8;
  f32x4 acc[4][4] = {};
  int kbeg = blockIdx.z * KS;
  if (EPI == 3) C += (size_t)blockIdx.z * M * N;
  for (int k0 = kbeg; k0 < kbeg + KS; k0 += 64) {
#pragma unroll
    for (int p = 0; p < 4; ++p) {
      int r0 = w * 32 + p * 8;
      int ga = bm + r0;
      if (ga > M - 8) ga = M - 8;     // clamp; LDS row untouched
      gload_lds16(A + (size_t)(ga + lrow) * K + k0 + lcol, &As[r0 * 64]);
      gload_lds16(Bt + (size_t)(bn + r0 + lrow) * K + k0 + lcol, &Bs[r0 * 64]);
    }
    __syncthreads();
#pragma unroll
    for (int kk = 0; kk < 64; kk += 32) {
      half8 af[4], bf[4];
#pragma unroll
      for (int i = 0; i < 4; ++i)
        af[i] = *(const half8*)(&As[(wm + i * 16 + l15) * 64 + kk + l4 * 8]);
#pragma unroll
      for (int j = 0; j < 4; ++j)
        bf[j] = *(const half8*)(&Bs[(wn + j * 16 + l15) * 64 + kk + l4 * 8]);
#pragma unroll
      for (int i = 0; i < 4; ++i)
#pragma unroll
        for (int j = 0; j < 4; ++j)
          acc[i][j] = __builtin_amdgcn_mfma_f32_16x16x32_f16(
              af[i], bf[j], acc[i][j], 0, 0, 0);
    }
    __syncthreads();
  }
#pragma unroll
  for (int i = 0; i < 4; ++i) {
#pragma unroll
    for (int j = 0; j < 4; ++j) {
#pragma unroll
      for (int r = 0; r < 4; ++r) {
        int row = bm + wm + i * 16 + l4 * 4 + r;
        int col = bn + wn + j * 16 + l15;
        if (row < M) {
          if (EPI == 3) {
            C[(size_t)row * N + col] = acc[i][j][r];
          } else {
            float val = acc[i][j][r] + bias[col];
            if (EPI == 0) {
              int crow = REMAP ? (row + row / 196 + 1) : row;
              C[(size_t)crow * N + col] = val;
            } else if (EPI == 1) {
              val = 0.5f * val * (1.0f + erff(val * 0.70710678118654752440f));
              ((unsigned short*)C)[(size_t)row * N + col] = f2h(val);
            } else {
              C[(size_t)row * N + col] += val;
            }
          }
        }
      }
    }
  }
}

// out += p0 + p1 + bias  (split-K reduce for MLP2)
__global__ __launch_bounds__(256) void mlp2_reduce(
    const float* __restrict__ p0, const float* __restrict__ p1,
    const float* __restrict__ bias, float* __restrict__ out) {
  size_t idx = ((size_t)blockIdx.x * 256 + threadIdx.x) * 4;  // < 6304*768
  int col = (int)(idx % VD);
  float4 a = *(const float4*)(p0 + idx);
  float4 b = *(const float4*)(p1 + idx);
  float4 bi = *(const float4*)(bias + col);
  float4 o = *(const float4*)(out + idx);
  o.x += a.x + b.x + bi.x;
  o.y += a.y + b.y + bi.y;
  o.z += a.z + b.z + bi.z;
  o.w += a.w + b.w + bi.w;
  *(float4*)(out + idx) = o;
}

// ---------------------------------------------------------------- classifier
__global__ __launch_bounds__(256) void cls_logits(
    const float* __restrict__ out_act, const float* __restrict__ Wc,
    const float* __restrict__ bc, float* __restrict__ lbuf) {
  int b = blockIdx.y;
  int n0 = blockIdx.x * 250;
  int t = threadIdx.x;
  __shared__ float xs[768];
  const float* xr = out_act + (size_t)b * VS * VD;  // cls token row
  xs[t] = xr[t]; xs[t + 256] = xr[t + 256]; xs[t + 512] = xr[t + 512];
  __syncthreads();
  if (t < 250) {
    int col = n0 + t;
    float acc = bc[col];
#pragma unroll 4
    for (int d = 0; d < VD; ++d) acc += xs[d] * Wc[(size_t)d * VOUT + col];
    lbuf[(size_t)b * VOUT + col] = acc;
  }
}

__global__ __launch_bounds__(256) void cls_softmax(
    const float* __restrict__ lbuf, float* __restrict__ y) {
  int b = blockIdx.x;
  int t = threadIdx.x;
  __shared__ float logit[VOUT];
  __shared__ float red[10];
  for (int j = t; j < VOUT; j += 256) logit[j] = lbuf[(size_t)b * VOUT + j];
  __syncthreads();
  float m = -1e30f;
  for (int j = t; j < VOUT; j += 256) m = fmaxf(m, logit[j]);
#pragma unroll
  for (int off = 32; off; off >>= 1) m = fmaxf(m, __shfl_down(m, off));
  if ((t & 63) == 0) red[t >> 6] = m;
  __syncthreads();
  if (t == 0) red[8] = fmaxf(fmaxf(red[0], red[1]), fmaxf(red[2], red[3]));
  __syncthreads();
  float M = red[8];
  float s = 0.f;
  for (int j = t; j < VOUT; j += 256) {
    float e = expf(logit[j] - M);
    logit[j] = e;
    s += e;
  }
#pragma unroll
  for (int off = 32; off; off >>= 1) s += __shfl_down(s, off);
  if ((t & 63) == 0) red[4 + (t >> 6)] = s;
  __syncthreads();
  if (t == 0) red[9] = red[4] + red[5] + red[6] + red[7];
  __syncthreads();
  float inv = 1.0f / red[9];
  for (int j = t; j < VOUT; j += 256) y[(size_t)b * VOUT + j] = logit[j] * inv;
}

// ---------------------------------------------------------------- launch
extern "C" void kernel_launch(void* const* d_in, const int* in_sizes, int n_in,
                              void* d_out, int out_size, void* d_ws, size_t ws_size,
                              hipStream_t stream) {
  const float* x      = (const float*)d_in[0];
  const float* cls    = (const float*)d_in[1];
  const float* pos    = (const float*)d_in[2];
  const float* Wmap   = (const float*)d_in[3];
  const float* bmap   = (const float*)d_in[4];
  const float* ln1_g  = (const float*)d_in[5];
  const float* ln1_b  = (const float*)d_in[6];
  const float* Wq     = (const float*)d_in[7];
  const float* bq     = (const float*)d_in[8];
  const float* Wk     = (const float*)d_in[9];
  const float* bk     = (const float*)d_in[10];
  const float* Wv     = (const float*)d_in[11];
  const float* bv     = (const float*)d_in[12];
  const float* ln2_g  = (const float*)d_in[13];
  const float* ln2_b  = (const float*)d_in[14];
  const float* W1     = (const float*)d_in[15];
  const float* b1     = (const float*)d_in[16];
  const float* W2     = (const float*)d_in[17];
  const float* b2     = (const float*)d_in[18];
  const float* Wc     = (const float*)d_in[19];
  const float* bc     = (const float*)d_in[20];
  float* yout = (float*)d_out;

  const size_t nBS  = (size_t)VB * VS;          // 6304
  const size_t nBSD = nBS * VD;                 // 4,841,472
  const size_t nQK  = (size_t)VB * VNH * VS * 64;   // 4,841,472
  char* base = (char*)d_ws;
  size_t off = 0;
  float* out_act = (float*)(base + off);      off += nBSD * 4;
  unsigned short* xnb = (unsigned short*)(base + off); off += nBSD * 2;
  unsigned short* qhb = (unsigned short*)(base + off); off += nQK * 2 + 65536;
  unsigned short* khb = (unsigned short*)(base + off); off += nQK * 2 + 65536;
  unsigned short* vtb = (unsigned short*)(base + off); off += (size_t)VB * VNH * 64 * 208 * 2;
  unsigned short* hbuf = (unsigned short*)(base + off); off += nBS * VMLP * 2;
  unsigned short* wmapT = (unsigned short*)(base + off); off += (size_t)VD * VD * 2;
  unsigned short* w1T = (unsigned short*)(base + off);   off += (size_t)VL * VMLP * VD * 2;
  unsigned short* w2T = (unsigned short*)(base + off);   off += (size_t)VL * VD * VMLP * 2;
  unsigned short* wqkv = (unsigned short*)(base + off);  off += (size_t)VL * VNH * 192 * 64 * 2;
  // split-K partials alias the (dead-during-MLP2) xnb/qhb/khb/vtb region
  float* part = (float*)xnb;                 // 2 * nBSD floats fit in 39.4 MB
  float* lbuf = (float*)qhb;                 // classifier logits (32x1000)

  // weight transposes / packs (fp32 -> fp16)
  transpose_kernel<<<dim3(12, 12, 1), 256, 0, stream>>>(Wmap, wmapT, VD, VD);
  transpose_kernel<<<dim3(48, 12, VL), 256, 0, stream>>>(W1, w1T, VD, VMLP);
  transpose_kernel<<<dim3(12, 48, VL), 256, 0, stream>>>(W2, w2T, VMLP, VD);
  pack_qkv_kernel<<<(VL * VNH * 192 * 64) / 256, 256, 0, stream>>>(Wq, Wk, Wv, wqkv);

  // patchify (fp16 patches into hbuf)
  patchify_kernel<<<VB * VNPAT, 256, 0, stream>>>(x, hbuf);
  // embed GEMM: out rows [b*197 + 1 + p]
  gemm_h<0, 1><<<dim3(6, 49), 256, 0, stream>>>(
      hbuf, wmapT, bmap, out_act, VB * VNPAT, VD, VD, VD);
  // cls token + positional embedding
  addpos_kernel<<<(int)nBS, 256, 0, stream>>>(cls, pos, out_act);

  for (int l = 0; l < VL; l++) {
    ln_kernel<<<(int)nBS, 256, 0, stream>>>(out_act, xnb,
                                            ln1_g + (size_t)l * VD,
                                            ln1_b + (size_t)l * VD);
    qkv_gemm<<<dim3(50, VNH), 256, 0, stream>>>(
        xnb, wqkv + (size_t)l * VNH * 192 * 64,
        bq + (size_t)l * VNH * VDH, bk + (size_t)l * VNH * VDH,
        bv + (size_t)l * VNH * VDH, qhb, khb, vtb);
    vt_ztail<<<(VB * VNH * 64 * 11) / 256, 256, 0, stream>>>(vtb);
    attn_mfma<<<dim3(VB * VNH, 4), 256, 0, stream>>>(qhb, khb, vtb, out_act);
    ln_kernel<<<(int)nBS, 256, 0, stream>>>(out_act, xnb,
                                            ln2_g + (size_t)l * VD,
                                            ln2_b + (size_t)l * VD);
    // MLP1: h = gelu(xn @ W1 + b1) -> fp16 hbuf
    gemm_h<1, 0><<<dim3(24, 50), 256, 0, stream>>>(
        xnb, w1T + (size_t)l * VMLP * VD, b1 + (size_t)l * VMLP,
        (float*)hbuf, (int)nBS, VMLP, VD, VD);
    // MLP2 split-K=2: partials then reduce (out += p0+p1+b2)
    gemm_h<3, 0><<<dim3(6, 50, 2), 256, 0, stream>>>(
        hbuf, w2T + (size_t)l * VD * VMLP, nullptr,
        part, (int)nBS, VD, VMLP, VMLP / 2);
    mlp2_reduce<<<(int)(nBSD / 1024), 256, 0, stream>>>(
        part, part + nBSD, b2 + (size_t)l * VD, out_act);
  }
  cls_logits<<<dim3(4, VB), 256, 0, stream>>>(out_act, Wc, bc, lbuf);
  cls_softmax<<<VB, 256, 0, stream>>>(lbuf, yout);
}